// Round 12
// baseline (302.052 us; speedup 1.0000x reference)
//
#include <hip/hip_runtime.h>

// ---------------- problem constants ----------------
#define NN   10000     // nodes
#define E0   160000    // raw edges
#define ET   170000    // edges + self loops
#define DIN  165       // input channels
#define KP   192       // DIN padded to 32x for MFMA K-loop
#define HID  1024      // 8 heads * 128
#define NH   8
#define BP   200       // LDS row pitch for gemm1 B-tile
#define K2P  1032      // LDS row pitch for gemm2 B

// dtypes (settled r6): ALL float tensors f32, edge_index int32, OUTPUT f32.

typedef __bf16 bf16x8 __attribute__((ext_vector_type(8)));
typedef float  f32x4  __attribute__((ext_vector_type(4)));

__device__ __forceinline__ float bf2f(unsigned short u) {
    unsigned int i = ((unsigned int)u) << 16;
    return __builtin_bit_cast(float, i);
}
__device__ __forceinline__ unsigned short f2bf(float f) {
    unsigned int i = __builtin_bit_cast(unsigned int, f);
    i += 0x7fffu + ((i >> 16) & 1u);   // round-to-nearest-even
    return (unsigned short)(i >> 16);
}
__device__ __forceinline__ float fin(float x) {
    return fminf(fmaxf(x, -1e30f), 1e30f);
}
__device__ __forceinline__ int clampi(int s) {
    return min(max(s, 0), NN - 1);
}
__device__ __forceinline__ void unpack8(uint4 u, float* f) {
    f[0]=bf2f((unsigned short)(u.x)); f[1]=bf2f((unsigned short)(u.x>>16));
    f[2]=bf2f((unsigned short)(u.y)); f[3]=bf2f((unsigned short)(u.y>>16));
    f[4]=bf2f((unsigned short)(u.z)); f[5]=bf2f((unsigned short)(u.z>>16));
    f[6]=bf2f((unsigned short)(u.w)); f[7]=bf2f((unsigned short)(u.w>>16));
}

// ---------------- debug ----------------
__global__ __launch_bounds__(256) void debug_fill(float* __restrict__ out, float val) {
    int i = blockIdx.x * 256 + threadIdx.x;
    if (i < NN) out[i] = val;
}

// ---------------- BN1: column stats over x [NN, DIN] f32 ----------------
__global__ __launch_bounds__(256) void bn1_stats(const float* __restrict__ x,
                                                 float* __restrict__ colsum, float* __restrict__ colsq) {
    int r0 = blockIdx.x * 125;
    int c = threadIdx.x;
    if (c >= DIN) return;
    float acc = 0.f, sq = 0.f;
    for (int r = r0; r < r0 + 125; ++r) {
        float v = x[(size_t)r * DIN + c];
        acc += v; sq += v * v;
    }
    atomicAdd(&colsum[c], acc);
    atomicAdd(&colsq[c], sq);
}

// normalized, K-padded hn [NN,KP] bf16; affine computed inline (r12: bn1_scale deleted)
__global__ __launch_bounds__(256) void bn1_apply(const float* __restrict__ x,
                                                 const float* __restrict__ colsum, const float* __restrict__ colsq,
                                                 const float* __restrict__ gamma, const float* __restrict__ beta,
                                                 unsigned short* __restrict__ hn) {
    int idx = blockIdx.x * 256 + threadIdx.x;   // NN*KP threads
    if (idx >= NN * KP) return;
    int r = idx / KP, c = idx - r * KP;
    float v = 0.f;
    if (c < DIN) {
        float mu  = colsum[c] * (1.f / NN);
        float var = fmaxf(colsq[c] * (1.f / NN) - mu * mu, 0.f);
        float a = gamma[c] * rsqrtf(var + 1e-5f);
        float b = beta[c] - mu * a;
        v = fin(x[(size_t)r * DIN + c] * a + b);
    }
    hn[idx] = f2bf(v);
}

// ---------------- GEMM1 (MFMA, LDS-staged B from f32 W): hn @ W -> xl,xr bf16 ------
// r12: stages B directly from f32 W1 (coalesced reads + cvt + transposed LDS write);
// w1_transpose kernel (4KB-stride uncoalesced reads) deleted.
__global__ __launch_bounds__(256) void gemm1_kernel(
    const unsigned short* __restrict__ hn,
    const float* __restrict__ Wl,   // [DIN][HID] f32
    const float* __restrict__ Wr,
    const float* __restrict__ bl,
    const float* __restrict__ br,
    unsigned short* __restrict__ xl,
    unsigned short* __restrict__ xr) {
    const float* wsrc    = blockIdx.z ? Wr : Wl;
    const float* bias    = blockIdx.z ? br : bl;
    unsigned short* xout = blockIdx.z ? xr : xl;

    __shared__ unsigned short bs[64 * BP];   // 25.6 KB, layout [tile-col][k]
    const int tid  = threadIdx.x;
    const int lane = tid & 63;
    const int wave = tid >> 6;
    const int col  = lane & 15;
    const int q    = lane >> 4;
    const int n0   = blockIdx.y * 64;

    // stage: bs[c][k] = bf16(W[k][n0+c]); k>=DIN zero-filled (MUST: uninit LDS could hold NaN)
    for (int idx = tid; idx < 64 * KP; idx += 256) {
        int k = idx >> 6;           // 0..191
        int c = idx & 63;
        float v = (k < DIN) ? wsrc[(size_t)k * HID + n0 + c] : 0.f;
        bs[c * BP + k] = f2bf(v);
    }
    __syncthreads();

    const int mbase = blockIdx.x * 128 + wave * 32;
    const int am0 = mbase + col;
    const int am1 = am0 + 16;
    const bool aok0 = (am0 < NN), aok1 = (am1 < NN);

    f32x4 acc[2][4];
    #pragma unroll
    for (int m = 0; m < 2; ++m)
        for (int nt = 0; nt < 4; ++nt)
            for (int r = 0; r < 4; ++r) acc[m][nt][r] = 0.f;

    #pragma unroll
    for (int kt = 0; kt < 6; ++kt) {
        const int kk = kt * 32 + q * 8;
        uint4 a0u = make_uint4(0u,0u,0u,0u), a1u = make_uint4(0u,0u,0u,0u);
        if (aok0) a0u = *(const uint4*)(hn + (size_t)am0 * KP + kk);
        if (aok1) a1u = *(const uint4*)(hn + (size_t)am1 * KP + kk);
        bf16x8 a0 = __builtin_bit_cast(bf16x8, a0u);
        bf16x8 a1 = __builtin_bit_cast(bf16x8, a1u);
        #pragma unroll
        for (int nt = 0; nt < 4; ++nt) {
            bf16x8 bf = __builtin_bit_cast(bf16x8, *(const uint4*)&bs[(nt * 16 + col) * BP + kk]);
            acc[0][nt] = __builtin_amdgcn_mfma_f32_16x16x32_bf16(a0, bf, acc[0][nt], 0, 0, 0);
            acc[1][nt] = __builtin_amdgcn_mfma_f32_16x16x32_bf16(a1, bf, acc[1][nt], 0, 0, 0);
        }
    }

    #pragma unroll
    for (int nt = 0; nt < 4; ++nt) {
        const int nc = n0 + nt * 16 + col;
        const float bv = bias[nc];
        #pragma unroll
        for (int m = 0; m < 2; ++m) {
            #pragma unroll
            for (int r = 0; r < 4; ++r) {
                const int row = mbase + m * 16 + q * 4 + r;
                if (row < NN)
                    xout[(size_t)row * HID + nc] = f2bf(fin(acc[m][nt][r] + bv));
            }
        }
    }
}

// ---------------- edge counting-sort by dst ----------------
__global__ __launch_bounds__(256) void edge_hist(const int* __restrict__ ei, int* __restrict__ deg) {
    int e = blockIdx.x * 256 + threadIdx.x;
    if (e >= ET) return;
    int d = (e < E0) ? ei[E0 + e] : (e - E0);
    atomicAdd(&deg[clampi(d)], 1);
}

// single-block scan, 10 elems/thread, 1 barrier
__global__ __launch_bounds__(1024) void scan_kernel(const int* __restrict__ deg,
                                                    int* __restrict__ offs, int* __restrict__ cur) {
    __shared__ int wsum[16];
    const int tid = threadIdx.x;
    const int base = tid * 10;
    int loc[10];
    int run = 0;
    #pragma unroll
    for (int j = 0; j < 10; ++j) {
        int idx = base + j;
        int v = (idx < NN) ? deg[idx] : 0;
        loc[j] = run;
        run += v;
    }
    const int lane = tid & 63;
    const int w = tid >> 6;
    int inc = run;
    #pragma unroll
    for (int s = 1; s < 64; s <<= 1) {
        int t = __shfl_up(inc, s);
        if (lane >= s) inc += t;
    }
    if (lane == 63) wsum[w] = inc;
    __syncthreads();
    int woff = 0;
    #pragma unroll
    for (int k = 0; k < 16; ++k) woff += (k < w) ? wsum[k] : 0;
    const int toff = woff + inc - run;
    #pragma unroll
    for (int j = 0; j < 10; ++j) {
        int idx = base + j;
        if (idx < NN) { int e = toff + loc[j]; offs[idx] = e; cur[idx] = e; }
    }
    if (tid == 1023) offs[NN] = woff + inc;
}

__global__ __launch_bounds__(256) void edge_scatter(const int* __restrict__ ei,
                                                    int* __restrict__ cur, int* __restrict__ ssrc) {
    int e = blockIdx.x * 256 + threadIdx.x;
    if (e >= ET) return;
    int s, d;
    if (e < E0) { s = ei[e]; d = ei[E0 + e]; }
    else        { s = e - E0; d = e - E0; }
    int pos = atomicAdd(&cur[clampi(d)], 1);
    if (pos >= 0 && pos < ET) ssrc[pos] = clampi(s);
}

// ---------------- GAT1 wave-per-node: logits+softmax+aggregate -> agg bf16 ----
// Registers only; alias (agg=xr1) safe by program order within the wave.
__global__ __launch_bounds__(256) void gat1_node(
    const unsigned short* __restrict__ xl1, const unsigned short* xr1,
    const float* __restrict__ att1, const float* __restrict__ bias1,
    const int* __restrict__ offs, const int* __restrict__ ssrc,
    unsigned short* agg) {
    const int lane = threadIdx.x & 63;
    const int wave = threadIdx.x >> 6;
    const int i = blockIdx.x * 4 + wave;   // grid = NN/4 exactly
    const int e0 = offs[i];
    const int e1 = max(offs[i + 1], e0);

    float xr_r[16], att_r[16];
    {
        const uint4* xp = (const uint4*)(xr1 + (size_t)i * HID + lane * 16);
        uint4 u0 = xp[0], u1 = xp[1];
        unpack8(u0, xr_r); unpack8(u1, xr_r + 8);
        const float4* ap = (const float4*)(att1 + lane * 16);
        float4 a0 = ap[0], a1 = ap[1], a2 = ap[2], a3 = ap[3];
        att_r[0]=a0.x; att_r[1]=a0.y; att_r[2]=a0.z; att_r[3]=a0.w;
        att_r[4]=a1.x; att_r[5]=a1.y; att_r[6]=a1.z; att_r[7]=a1.w;
        att_r[8]=a2.x; att_r[9]=a2.y; att_r[10]=a2.z; att_r[11]=a2.w;
        att_r[12]=a3.x; att_r[13]=a3.y; att_r[14]=a3.z; att_r[15]=a3.w;
    }

    float o[16];
    #pragma unroll
    for (int j = 0; j < 16; ++j) o[j] = 0.f;
    float s = 0.f;

    int e = e0;
    for (; e + 1 < e1; e += 2) {
        const int s0i = clampi(ssrc[e]);
        const int s1i = clampi(ssrc[e + 1]);
        const uint4* xp0 = (const uint4*)(xl1 + (size_t)s0i * HID + lane * 16);
        const uint4* xp1 = (const uint4*)(xl1 + (size_t)s1i * HID + lane * 16);
        uint4 a0 = xp0[0], a1 = xp0[1], b0 = xp1[0], b1 = xp1[1];
        float xv0[16], xv1[16];
        unpack8(a0, xv0); unpack8(a1, xv0 + 8);
        unpack8(b0, xv1); unpack8(b1, xv1 + 8);
        float p0 = 0.f, p1 = 0.f;
        #pragma unroll
        for (int j = 0; j < 16; ++j) {
            float v0 = xv0[j] + xr_r[j];
            float v1 = xv1[j] + xr_r[j];
            v0 = fmaxf(v0, 0.2f * v0);
            v1 = fmaxf(v1, 0.2f * v1);
            p0 = fmaf(att_r[j], v0, p0);
            p1 = fmaf(att_r[j], v1, p1);
        }
        p0 += __shfl_xor(p0, 1); p0 += __shfl_xor(p0, 2); p0 += __shfl_xor(p0, 4);
        p1 += __shfl_xor(p1, 1); p1 += __shfl_xor(p1, 2); p1 += __shfl_xor(p1, 4);
        const float aa0 = __expf(fminf(fin(p0), 50.f));
        const float aa1 = __expf(fminf(fin(p1), 50.f));
        s += aa0 + aa1;
        #pragma unroll
        for (int j = 0; j < 16; ++j) o[j] = fmaf(aa0, xv0[j], fmaf(aa1, xv1[j], o[j]));
    }
    if (e < e1) {
        const int sidx = clampi(ssrc[e]);
        const uint4* xp = (const uint4*)(xl1 + (size_t)sidx * HID + lane * 16);
        uint4 u0 = xp[0], u1 = xp[1];
        float xv[16];
        unpack8(u0, xv); unpack8(u1, xv + 8);
        float p = 0.f;
        #pragma unroll
        for (int j = 0; j < 16; ++j) {
            float v = xv[j] + xr_r[j];
            v = fmaxf(v, 0.2f * v);
            p = fmaf(att_r[j], v, p);
        }
        p += __shfl_xor(p, 1); p += __shfl_xor(p, 2); p += __shfl_xor(p, 4);
        const float a = __expf(fminf(fin(p), 50.f));
        s += a;
        #pragma unroll
        for (int j = 0; j < 16; ++j) o[j] = fmaf(a, xv[j], o[j]);
    }

    const float inv = 1.f / (s + 1e-16f);
    const float4* bp = (const float4*)(bias1 + lane * 16);
    float4 b0 = bp[0], b1 = bp[1], b2 = bp[2], b3 = bp[3];
    float bb[16] = {b0.x,b0.y,b0.z,b0.w, b1.x,b1.y,b1.z,b1.w,
                    b2.x,b2.y,b2.z,b2.w, b3.x,b3.y,b3.z,b3.w};
    unsigned short ov[16];
    #pragma unroll
    for (int j = 0; j < 16; ++j) ov[j] = f2bf(fin(o[j] * inv + bb[j]));
    uint4* op = (uint4*)(agg + (size_t)i * HID + lane * 16);
    op[0] = *(const uint4*)&ov[0];
    op[1] = *(const uint4*)&ov[8];
}

// ---------------- BN2 over agg [NN,HID] bf16 ----------------
__global__ __launch_bounds__(256) void bn2_stats(const unsigned short* __restrict__ agg,
                                                 float* __restrict__ colsum, float* __restrict__ colsq) {
    int r0 = blockIdx.x * 125;
    int t = threadIdx.x;
    float s0=0,s1=0,s2=0,s3=0,q0=0,q1=0,q2=0,q3=0;
    for (int r = r0; r < r0 + 125; ++r) {
        const ushort4 u = *(const ushort4*)(agg + (size_t)r * HID + t * 4);
        float v0=bf2f(u.x), v1=bf2f(u.y), v2=bf2f(u.z), v3=bf2f(u.w);
        s0+=v0; q0+=v0*v0; s1+=v1; q1+=v1*v1;
        s2+=v2; q2+=v2*v2; s3+=v3; q3+=v3*v3;
    }
    atomicAdd(&colsum[t*4+0], s0); atomicAdd(&colsq[t*4+0], q0);
    atomicAdd(&colsum[t*4+1], s1); atomicAdd(&colsq[t*4+1], q1);
    atomicAdd(&colsum[t*4+2], s2); atomicAdd(&colsq[t*4+2], q2);
    atomicAdd(&colsum[t*4+3], s3); atomicAdd(&colsq[t*4+3], q3);
}

// in-place BN affine + leaky(0.01); affine computed inline (r12: bn2_scale deleted)
__global__ __launch_bounds__(256) void bn2_apply(unsigned short* __restrict__ agg,
                                                 const float* __restrict__ colsum, const float* __restrict__ colsq,
                                                 const float* __restrict__ gamma, const float* __restrict__ beta) {
    int idx = blockIdx.x * 256 + threadIdx.x;
    int base = idx * 4;
    int c = base & (HID - 1);
    ushort4 u = *(const ushort4*)(agg + base);
    float4 cs = *(const float4*)(colsum + c);
    float4 cq = *(const float4*)(colsq + c);
    float4 g  = *(const float4*)(gamma + c);
    float4 bt = *(const float4*)(beta + c);
    float mu0 = cs.x*(1.f/NN), mu1 = cs.y*(1.f/NN), mu2 = cs.z*(1.f/NN), mu3 = cs.w*(1.f/NN);
    float a0 = g.x * rsqrtf(fmaxf(cq.x*(1.f/NN)-mu0*mu0, 0.f) + 1e-5f);
    float a1 = g.y * rsqrtf(fmaxf(cq.y*(1.f/NN)-mu1*mu1, 0.f) + 1e-5f);
    float a2 = g.z * rsqrtf(fmaxf(cq.z*(1.f/NN)-mu2*mu2, 0.f) + 1e-5f);
    float a3 = g.w * rsqrtf(fmaxf(cq.w*(1.f/NN)-mu3*mu3, 0.f) + 1e-5f);
    float o0 = bf2f(u.x)*a0 + (bt.x - mu0*a0);
    float o1 = bf2f(u.y)*a1 + (bt.y - mu1*a1);
    float o2 = bf2f(u.z)*a2 + (bt.z - mu2*a2);
    float o3 = bf2f(u.w)*a3 + (bt.w - mu3*a3);
    o0 = fmaxf(o0, 0.01f * o0); o1 = fmaxf(o1, 0.01f * o1);
    o2 = fmaxf(o2, 0.01f * o2); o3 = fmaxf(o3, 0.01f * o3);
    ushort4 o; o.x = f2bf(fin(o0)); o.y = f2bf(fin(o1)); o.z = f2bf(fin(o2)); o.w = f2bf(fin(o3));
    *(ushort4*)(agg + base) = o;
}

// ---------------- GEMM2 (MFMA): h2 [NN,HID] @ [Wl2|Wr2][HID,16] -> xl2|xr2 f32 -------
// r12: stages B directly from f32 Wl2/Wr2 (w2_prep kernel deleted).
__global__ __launch_bounds__(256) void gemm2_kernel(
    const unsigned short* __restrict__ h2,
    const float* __restrict__ wl2, const float* __restrict__ wr2,
    const float* __restrict__ bl2, const float* __restrict__ br2,
    float* __restrict__ xl2, float* __restrict__ xr2) {
    __shared__ unsigned short bs[16 * K2P];   // 33 KB
    const int tid  = threadIdx.x;
    const int lane = tid & 63;
    const int wave = tid >> 6;
    const int col  = lane & 15;
    const int q    = lane >> 4;

    // stage B: bs[n][k] = bf16(n<8 ? Wl2[k][n] : Wr2[k][n-8])
    for (int idx = tid; idx < 16 * HID; idx += 256) {
        int n = idx >> 10, k = idx & (HID - 1);
        float v = (n < 8) ? wl2[k * 8 + n] : wr2[k * 8 + (n - 8)];
        bs[n * K2P + k] = f2bf(v);
    }
    __syncthreads();

    const int mtile = blockIdx.x * 4 + wave;
    if (mtile >= NN / 16) return;
    const int m0 = mtile * 16;
    const int am = m0 + col;

    f32x4 acc;
    acc[0] = acc[1] = acc[2] = acc[3] = 0.f;
    #pragma unroll
    for (int kt = 0; kt < 32; ++kt) {
        const int kk = kt * 32 + q * 8;
        bf16x8 af = __builtin_bit_cast(bf16x8, *(const uint4*)(h2 + (size_t)am * HID + kk));
        bf16x8 bf = __builtin_bit_cast(bf16x8, *(const uint4*)&bs[col * K2P + kk]);
        acc = __builtin_amdgcn_mfma_f32_16x16x32_bf16(af, bf, acc, 0, 0, 0);
    }

    const float bv = (col < 8) ? bl2[col] : br2[col - 8];
    float* outp = (col < 8) ? (xl2 + col) : (xr2 + (col - 8));
    #pragma unroll
    for (int r = 0; r < 4; ++r) {
        const int row = m0 + q * 4 + r;
        outp[row * 8] = fin(acc[r] + bv);
    }
}

// ---------------- GAT2 single-pass (r12): no max-subtraction, clamp-50 ----------------
__global__ __launch_bounds__(256) void gat2_node(
    const float* __restrict__ xl2, const float* __restrict__ xr2,
    const float* __restrict__ att2, const float* __restrict__ bias2,
    const int* __restrict__ offs, const int* __restrict__ ssrc,
    float* __restrict__ out) {
    const int lane = threadIdx.x & 63;
    const int wave = threadIdx.x >> 6;
    const int i = blockIdx.x * 4 + wave;
    const int h = lane & 7, slot = lane >> 3;
    const int e0 = offs[i];
    const int e1 = max(offs[i + 1], e0);
    const float xr_h = xr2[i * 8 + h];
    const float att_h = att2[h];
    float ssum = 0.f, wsum = 0.f;
    for (int eb = e0; eb < e1; eb += 8) {
        int e = eb + slot;
        if (e < e1) {
            float xlv = xl2[clampi(ssrc[e]) * 8 + h];
            float v = xlv + xr_h;
            v = fmaxf(v, 0.2f * v);
            float a = __expf(fminf(fin(att_h * v), 50.f));
            ssum += a; wsum += a * xlv;
        }
    }
    ssum += __shfl_xor(ssum, 8); ssum += __shfl_xor(ssum, 16); ssum += __shfl_xor(ssum, 32);
    wsum += __shfl_xor(wsum, 8); wsum += __shfl_xor(wsum, 16); wsum += __shfl_xor(wsum, 32);
    float v = fin(wsum / (ssum + 1e-16f));
    v += __shfl_xor(v, 1); v += __shfl_xor(v, 2); v += __shfl_xor(v, 4);
    if (lane == 0) out[i] = fin(v * 0.125f + bias2[0]);
}

// ---------------- launch ----------------
extern "C" void kernel_launch(void* const* d_in, const int* in_sizes, int n_in,
                              void* d_out, int out_size, void* d_ws, size_t ws_size,
                              hipStream_t stream) {
    float* out = (float*)d_out;   // reference output dtype is float32

    static const int expected[18] = {
        NN * DIN, DIN, DIN, DIN * HID, HID, DIN * HID, HID, HID, HID,
        HID, HID, HID * NH, NH, HID * NH, NH, NH, 1, 2 * E0
    };
    if (n_in != 18) {
        debug_fill<<<(NN + 255) / 256, 256, 0, stream>>>(out, 8192.f + 64.f * (float)n_in);
        return;
    }
    for (int i = 0; i < 18; ++i) {
        if (in_sizes[i] != expected[i]) {
            debug_fill<<<(NN + 255) / 256, 256, 0, stream>>>(out, 4096.f + 32.f * (float)i);
            return;
        }
    }

    const float* x      = (const float*)d_in[0];
    const float* gamma1 = (const float*)d_in[1];
    const float* beta1  = (const float*)d_in[2];
    const float* Wl1    = (const float*)d_in[3];
    const float* bl1    = (const float*)d_in[4];
    const float* Wr1    = (const float*)d_in[5];
    const float* br1    = (const float*)d_in[6];
    const float* att1   = (const float*)d_in[7];
    const float* bias1  = (const float*)d_in[8];
    const float* gamma2 = (const float*)d_in[9];
    const float* beta2  = (const float*)d_in[10];
    const float* Wl2    = (const float*)d_in[11];
    const float* bl2    = (const float*)d_in[12];
    const float* Wr2    = (const float*)d_in[13];
    const float* br2    = (const float*)d_in[14];
    const float* att2   = (const float*)d_in[15];
    const float* bias2  = (const float*)d_in[16];
    const int*   ei     = (const int*)d_in[17];

    char* p = (char*)d_ws;
    auto alloc = [&](size_t bytes) -> void* {
        void* r = (void*)p;
        p += (bytes + 255) & ~(size_t)255;
        return r;
    };
    unsigned short* xl1  = (unsigned short*)alloc((size_t)NN * HID * 2);  // 20.48 MB
    unsigned short* xr1  = (unsigned short*)alloc((size_t)NN * HID * 2);  // 20.48 MB
    unsigned short* agg  = xr1;                                           // ALIAS (see gat1_node)
    unsigned short* hn   = (unsigned short*)alloc((size_t)NN * KP * 2);   // 3.84 MB
    float*          xl2  = (float*)alloc((size_t)NN * 8 * 4);
    float*          xr2  = (float*)alloc((size_t)NN * 8 * 4);
    int*            offs = (int*)alloc((NN + 1) * 4);
    int*            cur  = (int*)alloc(NN * 4);
    int*            ssrc = (int*)alloc(ET * 4);
    char* zbase = p;
    float* colsum1 = (float*)alloc(DIN * 4);
    float* colsq1  = (float*)alloc(DIN * 4);
    float* colsum2 = (float*)alloc(HID * 4);
    float* colsq2  = (float*)alloc(HID * 4);
    int*   deg     = (int*)alloc(NN * 4);
    size_t zlen = (size_t)(p - zbase);
    hipMemsetAsync(zbase, 0, zlen, stream);

    // 11 launches total (was 15): bn1_scale, w1_transpose, bn2_scale, w2_prep deleted.
    bn1_stats<<<80, 256, 0, stream>>>(x, colsum1, colsq1);
    bn1_apply<<<(NN * KP + 255) / 256, 256, 0, stream>>>(x, colsum1, colsq1, gamma1, beta1, hn);
    gemm1_kernel<<<dim3((NN + 127) / 128, HID / 64, 2), 256, 0, stream>>>(hn, Wl1, Wr1, bl1, br1, xl1, xr1);
    edge_hist<<<(ET + 255) / 256, 256, 0, stream>>>(ei, deg);
    scan_kernel<<<1, 1024, 0, stream>>>(deg, offs, cur);
    edge_scatter<<<(ET + 255) / 256, 256, 0, stream>>>(ei, cur, ssrc);
    gat1_node<<<NN / 4, 256, 0, stream>>>(xl1, xr1, att1, bias1, offs, ssrc, agg);
    bn2_stats<<<80, 256, 0, stream>>>(agg, colsum2, colsq2);
    bn2_apply<<<(NN * HID / 4 + 255) / 256, 256, 0, stream>>>(agg, colsum2, colsq2, gamma2, beta2);
    gemm2_kernel<<<(NN / 16 + 3) / 4, 256, 0, stream>>>(agg, Wl2, Wr2, bl2, br2, xl2, xr2);
    gat2_node<<<NN / 4, 256, 0, stream>>>(xl2, xr2, att2, bias2, offs, ssrc, out);
}

// Round 13
// 287.989 us; speedup vs baseline: 1.0488x; 1.0488x over previous
//
#include <hip/hip_runtime.h>

// ---------------- problem constants ----------------
#define NN   10000     // nodes
#define E0   160000    // raw edges
#define ET   170000    // edges + self loops
#define DIN  165       // input channels
#define KP   192       // DIN padded to 32x for MFMA K-loop
#define HID  1024      // 8 heads * 128
#define NH   8
#define BP   200       // LDS row pitch for gemm1 B-tile (conflict-free, 16B-aligned rows)
#define K2P  1032      // LDS row pitch for gemm2 B

// dtypes (settled r6): ALL float tensors f32, edge_index int32, OUTPUT f32.

typedef __bf16 bf16x8 __attribute__((ext_vector_type(8)));
typedef float  f32x4  __attribute__((ext_vector_type(4)));

__device__ __forceinline__ float bf2f(unsigned short u) {
    unsigned int i = ((unsigned int)u) << 16;
    return __builtin_bit_cast(float, i);
}
__device__ __forceinline__ unsigned short f2bf(float f) {
    unsigned int i = __builtin_bit_cast(unsigned int, f);
    i += 0x7fffu + ((i >> 16) & 1u);   // round-to-nearest-even
    return (unsigned short)(i >> 16);
}
__device__ __forceinline__ float fin(float x) {
    return fminf(fmaxf(x, -1e30f), 1e30f);
}
__device__ __forceinline__ int clampi(int s) {
    return min(max(s, 0), NN - 1);
}
__device__ __forceinline__ void unpack8(uint4 u, float* f) {
    f[0]=bf2f((unsigned short)(u.x)); f[1]=bf2f((unsigned short)(u.x>>16));
    f[2]=bf2f((unsigned short)(u.y)); f[3]=bf2f((unsigned short)(u.y>>16));
    f[4]=bf2f((unsigned short)(u.z)); f[5]=bf2f((unsigned short)(u.z>>16));
    f[6]=bf2f((unsigned short)(u.w)); f[7]=bf2f((unsigned short)(u.w>>16));
}

// ---------------- debug ----------------
__global__ __launch_bounds__(256) void debug_fill(float* __restrict__ out, float val) {
    int i = blockIdx.x * 256 + threadIdx.x;
    if (i < NN) out[i] = val;
}

// ---------------- BN1: column stats over x [NN, DIN] f32 ----------------
__global__ __launch_bounds__(256) void bn1_stats(const float* __restrict__ x,
                                                 float* __restrict__ colsum, float* __restrict__ colsq) {
    int r0 = blockIdx.x * 125;
    int c = threadIdx.x;
    if (c >= DIN) return;
    float acc = 0.f, sq = 0.f;
    for (int r = r0; r < r0 + 125; ++r) {
        float v = x[(size_t)r * DIN + c];
        acc += v; sq += v * v;
    }
    atomicAdd(&colsum[c], acc);
    atomicAdd(&colsq[c], sq);
}

// normalized, K-padded hn [NN,KP] bf16; affine computed inline
__global__ __launch_bounds__(256) void bn1_apply(const float* __restrict__ x,
                                                 const float* __restrict__ colsum, const float* __restrict__ colsq,
                                                 const float* __restrict__ gamma, const float* __restrict__ beta,
                                                 unsigned short* __restrict__ hn) {
    int idx = blockIdx.x * 256 + threadIdx.x;   // NN*KP threads
    if (idx >= NN * KP) return;
    int r = idx / KP, c = idx - r * KP;
    float v = 0.f;
    if (c < DIN) {
        float mu  = colsum[c] * (1.f / NN);
        float var = fmaxf(colsq[c] * (1.f / NN) - mu * mu, 0.f);
        float a = gamma[c] * rsqrtf(var + 1e-5f);
        float b = beta[c] - mu * a;
        v = fin(x[(size_t)r * DIN + c] * a + b);
    }
    hn[idx] = f2bf(v);
}

// ---------------- W1 transpose (r13: LDS-tiled, coalesced both sides) ----------------
// f32 [DIN][HID] -> bf16 [HID][KP]. Tile 32k x 64n via ts[32][65] (pitch 65 = 1 mod 32:
// transposed reads conflict-free). r12's in-gemm1 transpose had 8-way LDS write conflicts
// (3.88M cycles) -> this dedicated kernel pays the transpose cost once, coalesced.
__global__ __launch_bounds__(256) void w1_transpose(const float* __restrict__ wl,
                                                    const float* __restrict__ wr,
                                                    unsigned short* __restrict__ wlt,
                                                    unsigned short* __restrict__ wrt) {
    const float* src    = blockIdx.z ? wr  : wl;
    unsigned short* dst = blockIdx.z ? wrt : wlt;
    __shared__ float ts[32][65];
    const int k0 = blockIdx.x * 32;    // 6 tiles cover KP=192
    const int n0 = blockIdx.y * 64;    // 16 tiles cover HID=1024
    const int tid = threadIdx.x;
    for (int idx = tid; idx < 32 * 64; idx += 256) {
        int k = idx >> 6, n = idx & 63;
        ts[k][n] = (k0 + k < DIN) ? src[(size_t)(k0 + k) * HID + n0 + n] : 0.f;
    }
    __syncthreads();
    for (int idx = tid; idx < 64 * 32; idx += 256) {
        int n = idx >> 5, k = idx & 31;
        dst[(size_t)(n0 + n) * KP + k0 + k] = f2bf(ts[k][n]);
    }
}

// ---------------- GEMM1 (MFMA, LDS-staged bf16 B — r11 version): hn @ W -> xl,xr bf16 ----
__global__ __launch_bounds__(256) void gemm1_kernel(
    const unsigned short* __restrict__ hn,
    const unsigned short* __restrict__ wlt,  // [HID][KP] bf16
    const unsigned short* __restrict__ wrt,
    const float* __restrict__ bl,
    const float* __restrict__ br,
    unsigned short* __restrict__ xl,
    unsigned short* __restrict__ xr) {
    const unsigned short* wt = blockIdx.z ? wrt : wlt;
    const float* bias        = blockIdx.z ? br  : bl;
    unsigned short* xout     = blockIdx.z ? xr  : xl;

    __shared__ unsigned short bs[64 * BP];   // 25.6 KB
    const int tid  = threadIdx.x;
    const int lane = tid & 63;
    const int wave = tid >> 6;
    const int col  = lane & 15;
    const int q    = lane >> 4;
    const int n0   = blockIdx.y * 64;

    // stage B-tile: coalesced uint2 reads from pre-transposed wt, contiguous LDS writes
    for (int idx = tid; idx < 64 * 48; idx += 256) {
        int r = idx / 48, c = idx - r * 48;
        uint2 v = *(const uint2*)(wt + (size_t)(n0 + r) * KP + c * 4);
        *(uint2*)&bs[r * BP + c * 4] = v;
    }
    __syncthreads();

    const int mbase = blockIdx.x * 128 + wave * 32;
    const int am0 = mbase + col;
    const int am1 = am0 + 16;
    const bool aok0 = (am0 < NN), aok1 = (am1 < NN);

    f32x4 acc[2][4];
    #pragma unroll
    for (int m = 0; m < 2; ++m)
        for (int nt = 0; nt < 4; ++nt)
            for (int r = 0; r < 4; ++r) acc[m][nt][r] = 0.f;

    #pragma unroll
    for (int kt = 0; kt < 6; ++kt) {
        const int kk = kt * 32 + q * 8;
        uint4 a0u = make_uint4(0u,0u,0u,0u), a1u = make_uint4(0u,0u,0u,0u);
        if (aok0) a0u = *(const uint4*)(hn + (size_t)am0 * KP + kk);
        if (aok1) a1u = *(const uint4*)(hn + (size_t)am1 * KP + kk);
        bf16x8 a0 = __builtin_bit_cast(bf16x8, a0u);
        bf16x8 a1 = __builtin_bit_cast(bf16x8, a1u);
        #pragma unroll
        for (int nt = 0; nt < 4; ++nt) {
            bf16x8 bf = __builtin_bit_cast(bf16x8, *(const uint4*)&bs[(nt * 16 + col) * BP + kk]);
            acc[0][nt] = __builtin_amdgcn_mfma_f32_16x16x32_bf16(a0, bf, acc[0][nt], 0, 0, 0);
            acc[1][nt] = __builtin_amdgcn_mfma_f32_16x16x32_bf16(a1, bf, acc[1][nt], 0, 0, 0);
        }
    }

    #pragma unroll
    for (int nt = 0; nt < 4; ++nt) {
        const int nc = n0 + nt * 16 + col;
        const float bv = bias[nc];
        #pragma unroll
        for (int m = 0; m < 2; ++m) {
            #pragma unroll
            for (int r = 0; r < 4; ++r) {
                const int row = mbase + m * 16 + q * 4 + r;
                if (row < NN)
                    xout[(size_t)row * HID + nc] = f2bf(fin(acc[m][nt][r] + bv));
            }
        }
    }
}

// ---------------- edge counting-sort by dst ----------------
__global__ __launch_bounds__(256) void edge_hist(const int* __restrict__ ei, int* __restrict__ deg) {
    int e = blockIdx.x * 256 + threadIdx.x;
    if (e >= ET) return;
    int d = (e < E0) ? ei[E0 + e] : (e - E0);
    atomicAdd(&deg[clampi(d)], 1);
}

// single-block scan, 10 elems/thread, 1 barrier
__global__ __launch_bounds__(1024) void scan_kernel(const int* __restrict__ deg,
                                                    int* __restrict__ offs, int* __restrict__ cur) {
    __shared__ int wsum[16];
    const int tid = threadIdx.x;
    const int base = tid * 10;
    int loc[10];
    int run = 0;
    #pragma unroll
    for (int j = 0; j < 10; ++j) {
        int idx = base + j;
        int v = (idx < NN) ? deg[idx] : 0;
        loc[j] = run;
        run += v;
    }
    const int lane = tid & 63;
    const int w = tid >> 6;
    int inc = run;
    #pragma unroll
    for (int s = 1; s < 64; s <<= 1) {
        int t = __shfl_up(inc, s);
        if (lane >= s) inc += t;
    }
    if (lane == 63) wsum[w] = inc;
    __syncthreads();
    int woff = 0;
    #pragma unroll
    for (int k = 0; k < 16; ++k) woff += (k < w) ? wsum[k] : 0;
    const int toff = woff + inc - run;
    #pragma unroll
    for (int j = 0; j < 10; ++j) {
        int idx = base + j;
        if (idx < NN) { int e = toff + loc[j]; offs[idx] = e; cur[idx] = e; }
    }
    if (tid == 1023) offs[NN] = woff + inc;
}

__global__ __launch_bounds__(256) void edge_scatter(const int* __restrict__ ei,
                                                    int* __restrict__ cur, int* __restrict__ ssrc) {
    int e = blockIdx.x * 256 + threadIdx.x;
    if (e >= ET) return;
    int s, d;
    if (e < E0) { s = ei[e]; d = ei[E0 + e]; }
    else        { s = e - E0; d = e - E0; }
    int pos = atomicAdd(&cur[clampi(d)], 1);
    if (pos >= 0 && pos < ET) ssrc[pos] = clampi(s);
}

// ---------------- GAT1 wave-per-node: logits+softmax+aggregate -> agg bf16 ----
// Registers only; alias (agg=xr1) safe by program order within the wave.
__global__ __launch_bounds__(256) void gat1_node(
    const unsigned short* __restrict__ xl1, const unsigned short* xr1,
    const float* __restrict__ att1, const float* __restrict__ bias1,
    const int* __restrict__ offs, const int* __restrict__ ssrc,
    unsigned short* agg) {
    const int lane = threadIdx.x & 63;
    const int wave = threadIdx.x >> 6;
    const int i = blockIdx.x * 4 + wave;   // grid = NN/4 exactly
    const int e0 = offs[i];
    const int e1 = max(offs[i + 1], e0);

    float xr_r[16], att_r[16];
    {
        const uint4* xp = (const uint4*)(xr1 + (size_t)i * HID + lane * 16);
        uint4 u0 = xp[0], u1 = xp[1];
        unpack8(u0, xr_r); unpack8(u1, xr_r + 8);
        const float4* ap = (const float4*)(att1 + lane * 16);
        float4 a0 = ap[0], a1 = ap[1], a2 = ap[2], a3 = ap[3];
        att_r[0]=a0.x; att_r[1]=a0.y; att_r[2]=a0.z; att_r[3]=a0.w;
        att_r[4]=a1.x; att_r[5]=a1.y; att_r[6]=a1.z; att_r[7]=a1.w;
        att_r[8]=a2.x; att_r[9]=a2.y; att_r[10]=a2.z; att_r[11]=a2.w;
        att_r[12]=a3.x; att_r[13]=a3.y; att_r[14]=a3.z; att_r[15]=a3.w;
    }

    float o[16];
    #pragma unroll
    for (int j = 0; j < 16; ++j) o[j] = 0.f;
    float s = 0.f;

    int e = e0;
    for (; e + 1 < e1; e += 2) {
        const int s0i = clampi(ssrc[e]);
        const int s1i = clampi(ssrc[e + 1]);
        const uint4* xp0 = (const uint4*)(xl1 + (size_t)s0i * HID + lane * 16);
        const uint4* xp1 = (const uint4*)(xl1 + (size_t)s1i * HID + lane * 16);
        uint4 a0 = xp0[0], a1 = xp0[1], b0 = xp1[0], b1 = xp1[1];
        float xv0[16], xv1[16];
        unpack8(a0, xv0); unpack8(a1, xv0 + 8);
        unpack8(b0, xv1); unpack8(b1, xv1 + 8);
        float p0 = 0.f, p1 = 0.f;
        #pragma unroll
        for (int j = 0; j < 16; ++j) {
            float v0 = xv0[j] + xr_r[j];
            float v1 = xv1[j] + xr_r[j];
            v0 = fmaxf(v0, 0.2f * v0);
            v1 = fmaxf(v1, 0.2f * v1);
            p0 = fmaf(att_r[j], v0, p0);
            p1 = fmaf(att_r[j], v1, p1);
        }
        p0 += __shfl_xor(p0, 1); p0 += __shfl_xor(p0, 2); p0 += __shfl_xor(p0, 4);
        p1 += __shfl_xor(p1, 1); p1 += __shfl_xor(p1, 2); p1 += __shfl_xor(p1, 4);
        const float aa0 = __expf(fminf(fin(p0), 50.f));
        const float aa1 = __expf(fminf(fin(p1), 50.f));
        s += aa0 + aa1;
        #pragma unroll
        for (int j = 0; j < 16; ++j) o[j] = fmaf(aa0, xv0[j], fmaf(aa1, xv1[j], o[j]));
    }
    if (e < e1) {
        const int sidx = clampi(ssrc[e]);
        const uint4* xp = (const uint4*)(xl1 + (size_t)sidx * HID + lane * 16);
        uint4 u0 = xp[0], u1 = xp[1];
        float xv[16];
        unpack8(u0, xv); unpack8(u1, xv + 8);
        float p = 0.f;
        #pragma unroll
        for (int j = 0; j < 16; ++j) {
            float v = xv[j] + xr_r[j];
            v = fmaxf(v, 0.2f * v);
            p = fmaf(att_r[j], v, p);
        }
        p += __shfl_xor(p, 1); p += __shfl_xor(p, 2); p += __shfl_xor(p, 4);
        const float a = __expf(fminf(fin(p), 50.f));
        s += a;
        #pragma unroll
        for (int j = 0; j < 16; ++j) o[j] = fmaf(a, xv[j], o[j]);
    }

    const float inv = 1.f / (s + 1e-16f);
    const float4* bp = (const float4*)(bias1 + lane * 16);
    float4 b0 = bp[0], b1 = bp[1], b2 = bp[2], b3 = bp[3];
    float bb[16] = {b0.x,b0.y,b0.z,b0.w, b1.x,b1.y,b1.z,b1.w,
                    b2.x,b2.y,b2.z,b2.w, b3.x,b3.y,b3.z,b3.w};
    unsigned short ov[16];
    #pragma unroll
    for (int j = 0; j < 16; ++j) ov[j] = f2bf(fin(o[j] * inv + bb[j]));
    uint4* op = (uint4*)(agg + (size_t)i * HID + lane * 16);
    op[0] = *(const uint4*)&ov[0];
    op[1] = *(const uint4*)&ov[8];
}

// ---------------- BN2 over agg [NN,HID] bf16 ----------------
__global__ __launch_bounds__(256) void bn2_stats(const unsigned short* __restrict__ agg,
                                                 float* __restrict__ colsum, float* __restrict__ colsq) {
    int r0 = blockIdx.x * 125;
    int t = threadIdx.x;
    float s0=0,s1=0,s2=0,s3=0,q0=0,q1=0,q2=0,q3=0;
    for (int r = r0; r < r0 + 125; ++r) {
        const ushort4 u = *(const ushort4*)(agg + (size_t)r * HID + t * 4);
        float v0=bf2f(u.x), v1=bf2f(u.y), v2=bf2f(u.z), v3=bf2f(u.w);
        s0+=v0; q0+=v0*v0; s1+=v1; q1+=v1*v1;
        s2+=v2; q2+=v2*v2; s3+=v3; q3+=v3*v3;
    }
    atomicAdd(&colsum[t*4+0], s0); atomicAdd(&colsq[t*4+0], q0);
    atomicAdd(&colsum[t*4+1], s1); atomicAdd(&colsq[t*4+1], q1);
    atomicAdd(&colsum[t*4+2], s2); atomicAdd(&colsq[t*4+2], q2);
    atomicAdd(&colsum[t*4+3], s3); atomicAdd(&colsq[t*4+3], q3);
}

// in-place BN affine + leaky(0.01); affine computed inline
__global__ __launch_bounds__(256) void bn2_apply(unsigned short* __restrict__ agg,
                                                 const float* __restrict__ colsum, const float* __restrict__ colsq,
                                                 const float* __restrict__ gamma, const float* __restrict__ beta) {
    int idx = blockIdx.x * 256 + threadIdx.x;
    int base = idx * 4;
    int c = base & (HID - 1);
    ushort4 u = *(const ushort4*)(agg + base);
    float4 cs = *(const float4*)(colsum + c);
    float4 cq = *(const float4*)(colsq + c);
    float4 g  = *(const float4*)(gamma + c);
    float4 bt = *(const float4*)(beta + c);
    float mu0 = cs.x*(1.f/NN), mu1 = cs.y*(1.f/NN), mu2 = cs.z*(1.f/NN), mu3 = cs.w*(1.f/NN);
    float a0 = g.x * rsqrtf(fmaxf(cq.x*(1.f/NN)-mu0*mu0, 0.f) + 1e-5f);
    float a1 = g.y * rsqrtf(fmaxf(cq.y*(1.f/NN)-mu1*mu1, 0.f) + 1e-5f);
    float a2 = g.z * rsqrtf(fmaxf(cq.z*(1.f/NN)-mu2*mu2, 0.f) + 1e-5f);
    float a3 = g.w * rsqrtf(fmaxf(cq.w*(1.f/NN)-mu3*mu3, 0.f) + 1e-5f);
    float o0 = bf2f(u.x)*a0 + (bt.x - mu0*a0);
    float o1 = bf2f(u.y)*a1 + (bt.y - mu1*a1);
    float o2 = bf2f(u.z)*a2 + (bt.z - mu2*a2);
    float o3 = bf2f(u.w)*a3 + (bt.w - mu3*a3);
    o0 = fmaxf(o0, 0.01f * o0); o1 = fmaxf(o1, 0.01f * o1);
    o2 = fmaxf(o2, 0.01f * o2); o3 = fmaxf(o3, 0.01f * o3);
    ushort4 o; o.x = f2bf(fin(o0)); o.y = f2bf(fin(o1)); o.z = f2bf(fin(o2)); o.w = f2bf(fin(o3));
    *(ushort4*)(agg + base) = o;
}

// ---------------- GEMM2 (MFMA): h2 [NN,HID] @ [Wl2|Wr2][HID,16] -> xl2|xr2 f32 -------
__global__ __launch_bounds__(256) void gemm2_kernel(
    const unsigned short* __restrict__ h2,
    const float* __restrict__ wl2, const float* __restrict__ wr2,
    const float* __restrict__ bl2, const float* __restrict__ br2,
    float* __restrict__ xl2, float* __restrict__ xr2) {
    __shared__ unsigned short bs[16 * K2P];   // 33 KB
    const int tid  = threadIdx.x;
    const int lane = tid & 63;
    const int wave = tid >> 6;
    const int col  = lane & 15;
    const int q    = lane >> 4;

    for (int idx = tid; idx < 16 * HID; idx += 256) {
        int n = idx >> 10, k = idx & (HID - 1);
        float v = (n < 8) ? wl2[k * 8 + n] : wr2[k * 8 + (n - 8)];
        bs[n * K2P + k] = f2bf(v);
    }
    __syncthreads();

    const int mtile = blockIdx.x * 4 + wave;
    if (mtile >= NN / 16) return;
    const int m0 = mtile * 16;
    const int am = m0 + col;

    f32x4 acc;
    acc[0] = acc[1] = acc[2] = acc[3] = 0.f;
    #pragma unroll
    for (int kt = 0; kt < 32; ++kt) {
        const int kk = kt * 32 + q * 8;
        bf16x8 af = __builtin_bit_cast(bf16x8, *(const uint4*)(h2 + (size_t)am * HID + kk));
        bf16x8 bf = __builtin_bit_cast(bf16x8, *(const uint4*)&bs[col * K2P + kk]);
        acc = __builtin_amdgcn_mfma_f32_16x16x32_bf16(af, bf, acc, 0, 0, 0);
    }

    const float bv = (col < 8) ? bl2[col] : br2[col - 8];
    float* outp = (col < 8) ? (xl2 + col) : (xr2 + (col - 8));
    #pragma unroll
    for (int r = 0; r < 4; ++r) {
        const int row = m0 + q * 4 + r;
        outp[row * 8] = fin(acc[r] + bv);
    }
}

// ---------------- GAT2 single-pass: no max-subtraction, clamp-50 ----------------
__global__ __launch_bounds__(256) void gat2_node(
    const float* __restrict__ xl2, const float* __restrict__ xr2,
    const float* __restrict__ att2, const float* __restrict__ bias2,
    const int* __restrict__ offs, const int* __restrict__ ssrc,
    float* __restrict__ out) {
    const int lane = threadIdx.x & 63;
    const int wave = threadIdx.x >> 6;
    const int i = blockIdx.x * 4 + wave;
    const int h = lane & 7, slot = lane >> 3;
    const int e0 = offs[i];
    const int e1 = max(offs[i + 1], e0);
    const float xr_h = xr2[i * 8 + h];
    const float att_h = att2[h];
    float ssum = 0.f, wsum = 0.f;
    for (int eb = e0; eb < e1; eb += 8) {
        int e = eb + slot;
        if (e < e1) {
            float xlv = xl2[clampi(ssrc[e]) * 8 + h];
            float v = xlv + xr_h;
            v = fmaxf(v, 0.2f * v);
            float a = __expf(fminf(fin(att_h * v), 50.f));
            ssum += a; wsum += a * xlv;
        }
    }
    ssum += __shfl_xor(ssum, 8); ssum += __shfl_xor(ssum, 16); ssum += __shfl_xor(ssum, 32);
    wsum += __shfl_xor(wsum, 8); wsum += __shfl_xor(wsum, 16); wsum += __shfl_xor(wsum, 32);
    float v = fin(wsum / (ssum + 1e-16f));
    v += __shfl_xor(v, 1); v += __shfl_xor(v, 2); v += __shfl_xor(v, 4);
    if (lane == 0) out[i] = fin(v * 0.125f + bias2[0]);
}

// ---------------- launch ----------------
extern "C" void kernel_launch(void* const* d_in, const int* in_sizes, int n_in,
                              void* d_out, int out_size, void* d_ws, size_t ws_size,
                              hipStream_t stream) {
    float* out = (float*)d_out;   // reference output dtype is float32

    static const int expected[18] = {
        NN * DIN, DIN, DIN, DIN * HID, HID, DIN * HID, HID, HID, HID,
        HID, HID, HID * NH, NH, HID * NH, NH, NH, 1, 2 * E0
    };
    if (n_in != 18) {
        debug_fill<<<(NN + 255) / 256, 256, 0, stream>>>(out, 8192.f + 64.f * (float)n_in);
        return;
    }
    for (int i = 0; i < 18; ++i) {
        if (in_sizes[i] != expected[i]) {
            debug_fill<<<(NN + 255) / 256, 256, 0, stream>>>(out, 4096.f + 32.f * (float)i);
            return;
        }
    }

    const float* x      = (const float*)d_in[0];
    const float* gamma1 = (const float*)d_in[1];
    const float* beta1  = (const float*)d_in[2];
    const float* Wl1    = (const float*)d_in[3];
    const float* bl1    = (const float*)d_in[4];
    const float* Wr1    = (const float*)d_in[5];
    const float* br1    = (const float*)d_in[6];
    const float* att1   = (const float*)d_in[7];
    const float* bias1  = (const float*)d_in[8];
    const float* gamma2 = (const float*)d_in[9];
    const float* beta2  = (const float*)d_in[10];
    const float* Wl2    = (const float*)d_in[11];
    const float* bl2    = (const float*)d_in[12];
    const float* Wr2    = (const float*)d_in[13];
    const float* br2    = (const float*)d_in[14];
    const float* att2   = (const float*)d_in[15];
    const float* bias2  = (const float*)d_in[16];
    const int*   ei     = (const int*)d_in[17];

    char* p = (char*)d_ws;
    auto alloc = [&](size_t bytes) -> void* {
        void* r = (void*)p;
        p += (bytes + 255) & ~(size_t)255;
        return r;
    };
    unsigned short* xl1  = (unsigned short*)alloc((size_t)NN * HID * 2);  // 20.48 MB
    unsigned short* xr1  = (unsigned short*)alloc((size_t)NN * HID * 2);  // 20.48 MB
    unsigned short* agg  = xr1;                                           // ALIAS (see gat1_node)
    unsigned short* hn   = (unsigned short*)alloc((size_t)NN * KP * 2);   // 3.84 MB
    unsigned short* wlt  = (unsigned short*)alloc((size_t)HID * KP * 2);  // 0.39 MB
    unsigned short* wrt  = (unsigned short*)alloc((size_t)HID * KP * 2);  // 0.39 MB
    float*          xl2  = (float*)alloc((size_t)NN * 8 * 4);
    float*          xr2  = (float*)alloc((size_t)NN * 8 * 4);
    int*            offs = (int*)alloc((NN + 1) * 4);
    int*            cur  = (int*)alloc(NN * 4);
    int*            ssrc = (int*)alloc(ET * 4);
    char* zbase = p;
    float* colsum1 = (float*)alloc(DIN * 4);
    float* colsq1  = (float*)alloc(DIN * 4);
    float* colsum2 = (float*)alloc(HID * 4);
    float* colsq2  = (float*)alloc(HID * 4);
    int*   deg     = (int*)alloc(NN * 4);
    size_t zlen = (size_t)(p - zbase);
    hipMemsetAsync(zbase, 0, zlen, stream);

    // 12 launches (r13: tiled w1_transpose back; r11 gemm1; r12's other deletions kept)
    bn1_stats<<<80, 256, 0, stream>>>(x, colsum1, colsq1);
    bn1_apply<<<(NN * KP + 255) / 256, 256, 0, stream>>>(x, colsum1, colsq1, gamma1, beta1, hn);
    w1_transpose<<<dim3(6, 16, 2), 256, 0, stream>>>(Wl1, Wr1, wlt, wrt);
    gemm1_kernel<<<dim3((NN + 127) / 128, HID / 64, 2), 256, 0, stream>>>(hn, wlt, wrt, bl1, br1, xl1, xr1);
    edge_hist<<<(ET + 255) / 256, 256, 0, stream>>>(ei, deg);
    scan_kernel<<<1, 1024, 0, stream>>>(deg, offs, cur);
    edge_scatter<<<(ET + 255) / 256, 256, 0, stream>>>(ei, cur, ssrc);
    gat1_node<<<NN / 4, 256, 0, stream>>>(xl1, xr1, att1, bias1, offs, ssrc, agg);
    bn2_stats<<<80, 256, 0, stream>>>(agg, colsum2, colsq2);
    bn2_apply<<<(NN * HID / 4 + 255) / 256, 256, 0, stream>>>(agg, colsum2, colsq2, gamma2, beta2);
    gemm2_kernel<<<(NN / 16 + 3) / 4, 256, 0, stream>>>(agg, Wl2, Wr2, bl2, br2, xl2, xr2);
    gat2_node<<<NN / 4, 256, 0, stream>>>(xl2, xr2, att2, bias2, offs, ssrc, out);
}

// Round 14
// 282.715 us; speedup vs baseline: 1.0684x; 1.0187x over previous
//
#include <hip/hip_runtime.h>

// ---------------- problem constants ----------------
#define NN   10000     // nodes
#define E0   160000    // raw edges
#define ET   170000    // edges + self loops
#define DIN  165       // input channels
#define KP   192       // DIN padded to 32x for MFMA K-loop
#define HID  1024      // 8 heads * 128
#define NH   8
#define BP   200       // LDS row pitch for gemm1 B-tile (conflict-free, 16B-aligned rows)
#define K2P  1032      // LDS row pitch for gemm2 B

// dtypes (settled r6): ALL float tensors f32, edge_index int32, OUTPUT f32.

typedef __bf16 bf16x8 __attribute__((ext_vector_type(8)));
typedef float  f32x4  __attribute__((ext_vector_type(4)));

__device__ __forceinline__ float bf2f(unsigned short u) {
    unsigned int i = ((unsigned int)u) << 16;
    return __builtin_bit_cast(float, i);
}
__device__ __forceinline__ unsigned short f2bf(float f) {
    unsigned int i = __builtin_bit_cast(unsigned int, f);
    i += 0x7fffu + ((i >> 16) & 1u);   // round-to-nearest-even
    return (unsigned short)(i >> 16);
}
__device__ __forceinline__ float fin(float x) {
    return fminf(fmaxf(x, -1e30f), 1e30f);
}
__device__ __forceinline__ int clampi(int s) {
    return min(max(s, 0), NN - 1);
}
__device__ __forceinline__ void unpack8(uint4 u, float* f) {
    f[0]=bf2f((unsigned short)(u.x)); f[1]=bf2f((unsigned short)(u.x>>16));
    f[2]=bf2f((unsigned short)(u.y)); f[3]=bf2f((unsigned short)(u.y>>16));
    f[4]=bf2f((unsigned short)(u.z)); f[5]=bf2f((unsigned short)(u.z>>16));
    f[6]=bf2f((unsigned short)(u.w)); f[7]=bf2f((unsigned short)(u.w>>16));
}

// ---------------- debug ----------------
__global__ __launch_bounds__(256) void debug_fill(float* __restrict__ out, float val) {
    int i = blockIdx.x * 256 + threadIdx.x;
    if (i < NN) out[i] = val;
}

// ---------------- BN1: column stats over x [NN, DIN] f32 ----------------
__global__ __launch_bounds__(256) void bn1_stats(const float* __restrict__ x,
                                                 float* __restrict__ colsum, float* __restrict__ colsq) {
    int r0 = blockIdx.x * 125;
    int c = threadIdx.x;
    if (c >= DIN) return;
    float acc = 0.f, sq = 0.f;
    for (int r = r0; r < r0 + 125; ++r) {
        float v = x[(size_t)r * DIN + c];
        acc += v; sq += v * v;
    }
    atomicAdd(&colsum[c], acc);
    atomicAdd(&colsq[c], sq);
}

// normalized, K-padded hn [NN,KP] bf16; affine computed inline
__global__ __launch_bounds__(256) void bn1_apply(const float* __restrict__ x,
                                                 const float* __restrict__ colsum, const float* __restrict__ colsq,
                                                 const float* __restrict__ gamma, const float* __restrict__ beta,
                                                 unsigned short* __restrict__ hn) {
    int idx = blockIdx.x * 256 + threadIdx.x;   // NN*KP threads
    if (idx >= NN * KP) return;
    int r = idx / KP, c = idx - r * KP;
    float v = 0.f;
    if (c < DIN) {
        float mu  = colsum[c] * (1.f / NN);
        float var = fmaxf(colsq[c] * (1.f / NN) - mu * mu, 0.f);
        float a = gamma[c] * rsqrtf(var + 1e-5f);
        float b = beta[c] - mu * a;
        v = fin(x[(size_t)r * DIN + c] * a + b);
    }
    hn[idx] = f2bf(v);
}

// ---------------- W1 transpose (LDS-tiled, coalesced both sides) ----------------
__global__ __launch_bounds__(256) void w1_transpose(const float* __restrict__ wl,
                                                    const float* __restrict__ wr,
                                                    unsigned short* __restrict__ wlt,
                                                    unsigned short* __restrict__ wrt) {
    const float* src    = blockIdx.z ? wr  : wl;
    unsigned short* dst = blockIdx.z ? wrt : wlt;
    __shared__ float ts[32][65];
    const int k0 = blockIdx.x * 32;
    const int n0 = blockIdx.y * 64;
    const int tid = threadIdx.x;
    for (int idx = tid; idx < 32 * 64; idx += 256) {
        int k = idx >> 6, n = idx & 63;
        ts[k][n] = (k0 + k < DIN) ? src[(size_t)(k0 + k) * HID + n0 + n] : 0.f;
    }
    __syncthreads();
    for (int idx = tid; idx < 64 * 32; idx += 256) {
        int n = idx >> 5, k = idx & 31;
        dst[(size_t)(n0 + n) * KP + k0 + k] = f2bf(ts[k][n]);
    }
}

// ---------------- GEMM1 (MFMA, LDS-staged bf16 B): hn @ W -> xl,xr bf16 ----
__global__ __launch_bounds__(256) void gemm1_kernel(
    const unsigned short* __restrict__ hn,
    const unsigned short* __restrict__ wlt,  // [HID][KP] bf16
    const unsigned short* __restrict__ wrt,
    const float* __restrict__ bl,
    const float* __restrict__ br,
    unsigned short* __restrict__ xl,
    unsigned short* __restrict__ xr) {
    const unsigned short* wt = blockIdx.z ? wrt : wlt;
    const float* bias        = blockIdx.z ? br  : bl;
    unsigned short* xout     = blockIdx.z ? xr  : xl;

    __shared__ unsigned short bs[64 * BP];   // 25.6 KB
    const int tid  = threadIdx.x;
    const int lane = tid & 63;
    const int wave = tid >> 6;
    const int col  = lane & 15;
    const int q    = lane >> 4;
    const int n0   = blockIdx.y * 64;

    for (int idx = tid; idx < 64 * 48; idx += 256) {
        int r = idx / 48, c = idx - r * 48;
        uint2 v = *(const uint2*)(wt + (size_t)(n0 + r) * KP + c * 4);
        *(uint2*)&bs[r * BP + c * 4] = v;
    }
    __syncthreads();

    const int mbase = blockIdx.x * 128 + wave * 32;
    const int am0 = mbase + col;
    const int am1 = am0 + 16;
    const bool aok0 = (am0 < NN), aok1 = (am1 < NN);

    f32x4 acc[2][4];
    #pragma unroll
    for (int m = 0; m < 2; ++m)
        for (int nt = 0; nt < 4; ++nt)
            for (int r = 0; r < 4; ++r) acc[m][nt][r] = 0.f;

    #pragma unroll
    for (int kt = 0; kt < 6; ++kt) {
        const int kk = kt * 32 + q * 8;
        uint4 a0u = make_uint4(0u,0u,0u,0u), a1u = make_uint4(0u,0u,0u,0u);
        if (aok0) a0u = *(const uint4*)(hn + (size_t)am0 * KP + kk);
        if (aok1) a1u = *(const uint4*)(hn + (size_t)am1 * KP + kk);
        bf16x8 a0 = __builtin_bit_cast(bf16x8, a0u);
        bf16x8 a1 = __builtin_bit_cast(bf16x8, a1u);
        #pragma unroll
        for (int nt = 0; nt < 4; ++nt) {
            bf16x8 bf = __builtin_bit_cast(bf16x8, *(const uint4*)&bs[(nt * 16 + col) * BP + kk]);
            acc[0][nt] = __builtin_amdgcn_mfma_f32_16x16x32_bf16(a0, bf, acc[0][nt], 0, 0, 0);
            acc[1][nt] = __builtin_amdgcn_mfma_f32_16x16x32_bf16(a1, bf, acc[1][nt], 0, 0, 0);
        }
    }

    #pragma unroll
    for (int nt = 0; nt < 4; ++nt) {
        const int nc = n0 + nt * 16 + col;
        const float bv = bias[nc];
        #pragma unroll
        for (int m = 0; m < 2; ++m) {
            #pragma unroll
            for (int r = 0; r < 4; ++r) {
                const int row = mbase + m * 16 + q * 4 + r;
                if (row < NN)
                    xout[(size_t)row * HID + nc] = f2bf(fin(acc[m][nt][r] + bv));
            }
        }
    }
}

// ---------------- edge counting-sort by dst ----------------
__global__ __launch_bounds__(256) void edge_hist(const int* __restrict__ ei, int* __restrict__ deg) {
    int e = blockIdx.x * 256 + threadIdx.x;
    if (e >= ET) return;
    int d = (e < E0) ? ei[E0 + e] : (e - E0);
    atomicAdd(&deg[clampi(d)], 1);
}

// single-block scan + degree-descending node permutation (r14)
__global__ __launch_bounds__(1024) void scan_kernel(const int* __restrict__ deg,
                                                    int* __restrict__ offs, int* __restrict__ cur,
                                                    int* __restrict__ perm) {
    __shared__ int wsum[16];
    __shared__ int bins[64];
    __shared__ int bcur[64];
    const int tid = threadIdx.x;
    const int base = tid * 10;
    int loc[10];
    int run = 0;
    #pragma unroll
    for (int j = 0; j < 10; ++j) {
        int idx = base + j;
        int v = (idx < NN) ? deg[idx] : 0;
        loc[j] = run;
        run += v;
    }
    const int lane = tid & 63;
    const int w = tid >> 6;
    int inc = run;
    #pragma unroll
    for (int s = 1; s < 64; s <<= 1) {
        int t = __shfl_up(inc, s);
        if (lane >= s) inc += t;
    }
    if (lane == 63) wsum[w] = inc;
    if (tid < 64) bins[tid] = 0;
    __syncthreads();
    int woff = 0;
    #pragma unroll
    for (int k = 0; k < 16; ++k) woff += (k < w) ? wsum[k] : 0;
    const int toff = woff + inc - run;
    #pragma unroll
    for (int j = 0; j < 10; ++j) {
        int idx = base + j;
        if (idx < NN) {
            int e = toff + loc[j]; offs[idx] = e; cur[idx] = e;
            atomicAdd(&bins[63 - min(deg[idx], 63)], 1);   // descending-degree bucket
        }
    }
    if (tid == 1023) offs[NN] = woff + inc;
    __syncthreads();
    if (tid < 64) {   // wave 0: exclusive scan of 64 bins
        int v = bins[tid];
        int binc = v;
        #pragma unroll
        for (int s = 1; s < 64; s <<= 1) {
            int t = __shfl_up(binc, s);
            if (tid >= s) binc += t;
        }
        bcur[tid] = binc - v;
    }
    __syncthreads();
    #pragma unroll
    for (int j = 0; j < 10; ++j) {
        int idx = base + j;
        if (idx < NN) {
            int pos = atomicAdd(&bcur[63 - min(deg[idx], 63)], 1);
            perm[pos] = idx;
        }
    }
}

__global__ __launch_bounds__(256) void edge_scatter(const int* __restrict__ ei,
                                                    int* __restrict__ cur, int* __restrict__ ssrc) {
    int e = blockIdx.x * 256 + threadIdx.x;
    if (e >= ET) return;
    int s, d;
    if (e < E0) { s = ei[e]; d = ei[E0 + e]; }
    else        { s = e - E0; d = e - E0; }
    int pos = atomicAdd(&cur[clampi(d)], 1);
    if (pos >= 0 && pos < ET) ssrc[pos] = clampi(s);
}

// ---------------- GAT1 wave-per-node (degree-sorted order): -> agg bf16 ----
// Registers only; alias (agg=xr1) safe by program order within the wave (same row i).
__global__ __launch_bounds__(256) void gat1_node(
    const unsigned short* __restrict__ xl1, const unsigned short* xr1,
    const float* __restrict__ att1, const float* __restrict__ bias1,
    const int* __restrict__ offs, const int* __restrict__ ssrc,
    const int* __restrict__ perm,
    unsigned short* agg) {
    const int lane = threadIdx.x & 63;
    const int wave = threadIdx.x >> 6;
    const int i = perm[blockIdx.x * 4 + wave];   // degree-descending: long nodes start first
    const int e0 = offs[i];
    const int e1 = max(offs[i + 1], e0);

    float xr_r[16], att_r[16];
    {
        const uint4* xp = (const uint4*)(xr1 + (size_t)i * HID + lane * 16);
        uint4 u0 = xp[0], u1 = xp[1];
        unpack8(u0, xr_r); unpack8(u1, xr_r + 8);
        const float4* ap = (const float4*)(att1 + lane * 16);
        float4 a0 = ap[0], a1 = ap[1], a2 = ap[2], a3 = ap[3];
        att_r[0]=a0.x; att_r[1]=a0.y; att_r[2]=a0.z; att_r[3]=a0.w;
        att_r[4]=a1.x; att_r[5]=a1.y; att_r[6]=a1.z; att_r[7]=a1.w;
        att_r[8]=a2.x; att_r[9]=a2.y; att_r[10]=a2.z; att_r[11]=a2.w;
        att_r[12]=a3.x; att_r[13]=a3.y; att_r[14]=a3.z; att_r[15]=a3.w;
    }

    float o[16];
    #pragma unroll
    for (int j = 0; j < 16; ++j) o[j] = 0.f;
    float s = 0.f;

    int e = e0;
    for (; e + 1 < e1; e += 2) {
        const int s0i = clampi(ssrc[e]);
        const int s1i = clampi(ssrc[e + 1]);
        const uint4* xp0 = (const uint4*)(xl1 + (size_t)s0i * HID + lane * 16);
        const uint4* xp1 = (const uint4*)(xl1 + (size_t)s1i * HID + lane * 16);
        uint4 a0 = xp0[0], a1 = xp0[1], b0 = xp1[0], b1 = xp1[1];
        float xv0[16], xv1[16];
        unpack8(a0, xv0); unpack8(a1, xv0 + 8);
        unpack8(b0, xv1); unpack8(b1, xv1 + 8);
        float p0 = 0.f, p1 = 0.f;
        #pragma unroll
        for (int j = 0; j < 16; ++j) {
            float v0 = xv0[j] + xr_r[j];
            float v1 = xv1[j] + xr_r[j];
            v0 = fmaxf(v0, 0.2f * v0);
            v1 = fmaxf(v1, 0.2f * v1);
            p0 = fmaf(att_r[j], v0, p0);
            p1 = fmaf(att_r[j], v1, p1);
        }
        p0 += __shfl_xor(p0, 1); p0 += __shfl_xor(p0, 2); p0 += __shfl_xor(p0, 4);
        p1 += __shfl_xor(p1, 1); p1 += __shfl_xor(p1, 2); p1 += __shfl_xor(p1, 4);
        const float aa0 = __expf(fminf(fin(p0), 50.f));
        const float aa1 = __expf(fminf(fin(p1), 50.f));
        s += aa0 + aa1;
        #pragma unroll
        for (int j = 0; j < 16; ++j) o[j] = fmaf(aa0, xv0[j], fmaf(aa1, xv1[j], o[j]));
    }
    if (e < e1) {
        const int sidx = clampi(ssrc[e]);
        const uint4* xp = (const uint4*)(xl1 + (size_t)sidx * HID + lane * 16);
        uint4 u0 = xp[0], u1 = xp[1];
        float xv[16];
        unpack8(u0, xv); unpack8(u1, xv + 8);
        float p = 0.f;
        #pragma unroll
        for (int j = 0; j < 16; ++j) {
            float v = xv[j] + xr_r[j];
            v = fmaxf(v, 0.2f * v);
            p = fmaf(att_r[j], v, p);
        }
        p += __shfl_xor(p, 1); p += __shfl_xor(p, 2); p += __shfl_xor(p, 4);
        const float a = __expf(fminf(fin(p), 50.f));
        s += a;
        #pragma unroll
        for (int j = 0; j < 16; ++j) o[j] = fmaf(a, xv[j], o[j]);
    }

    const float inv = 1.f / (s + 1e-16f);
    const float4* bp = (const float4*)(bias1 + lane * 16);
    float4 b0 = bp[0], b1 = bp[1], b2 = bp[2], b3 = bp[3];
    float bb[16] = {b0.x,b0.y,b0.z,b0.w, b1.x,b1.y,b1.z,b1.w,
                    b2.x,b2.y,b2.z,b2.w, b3.x,b3.y,b3.z,b3.w};
    unsigned short ov[16];
    #pragma unroll
    for (int j = 0; j < 16; ++j) ov[j] = f2bf(fin(o[j] * inv + bb[j]));
    uint4* op = (uint4*)(agg + (size_t)i * HID + lane * 16);
    op[0] = *(const uint4*)&ov[0];
    op[1] = *(const uint4*)&ov[8];
}

// ---------------- BN2 stats over agg [NN,HID] bf16 ----------------
__global__ __launch_bounds__(256) void bn2_stats(const unsigned short* __restrict__ agg,
                                                 float* __restrict__ colsum, float* __restrict__ colsq) {
    int r0 = blockIdx.x * 125;
    int t = threadIdx.x;
    float s0=0,s1=0,s2=0,s3=0,q0=0,q1=0,q2=0,q3=0;
    for (int r = r0; r < r0 + 125; ++r) {
        const ushort4 u = *(const ushort4*)(agg + (size_t)r * HID + t * 4);
        float v0=bf2f(u.x), v1=bf2f(u.y), v2=bf2f(u.z), v3=bf2f(u.w);
        s0+=v0; q0+=v0*v0; s1+=v1; q1+=v1*v1;
        s2+=v2; q2+=v2*v2; s3+=v3; q3+=v3*v3;
    }
    atomicAdd(&colsum[t*4+0], s0); atomicAdd(&colsq[t*4+0], q0);
    atomicAdd(&colsum[t*4+1], s1); atomicAdd(&colsq[t*4+1], q1);
    atomicAdd(&colsum[t*4+2], s2); atomicAdd(&colsq[t*4+2], q2);
    atomicAdd(&colsum[t*4+3], s3); atomicAdd(&colsq[t*4+3], q3);
}

// ---------------- GEMM2 (MFMA, r14: BN2 affine + leaky fused into A-path) -----------
// agg bf16 -> affine (from colsum2/colsq2) -> leaky(0.01) -> bf16 A-frag -> MFMA.
// Deletes the 41MB bn2_apply round trip; numerics identical (same f32 chain + f2bf).
__global__ __launch_bounds__(256) void gemm2_kernel(
    const unsigned short* __restrict__ agg,
    const float* __restrict__ colsum, const float* __restrict__ colsq,
    const float* __restrict__ gamma, const float* __restrict__ beta,
    const float* __restrict__ wl2, const float* __restrict__ wr2,
    const float* __restrict__ bl2, const float* __restrict__ br2,
    float* __restrict__ xl2, float* __restrict__ xr2) {
    __shared__ unsigned short bs[16 * K2P];   // 33 KB
    __shared__ float a2s[HID], b2s[HID];      // 8 KB affine table
    const int tid  = threadIdx.x;
    const int lane = tid & 63;
    const int wave = tid >> 6;
    const int col  = lane & 15;
    const int q    = lane >> 4;

    for (int idx = tid; idx < 16 * HID; idx += 256) {
        int n = idx >> 10, k = idx & (HID - 1);
        float v = (n < 8) ? wl2[k * 8 + n] : wr2[k * 8 + (n - 8)];
        bs[n * K2P + k] = f2bf(v);
    }
    for (int c = tid; c < HID; c += 256) {
        float mu  = colsum[c] * (1.f / NN);
        float var = fmaxf(colsq[c] * (1.f / NN) - mu * mu, 0.f);
        float a = gamma[c] * rsqrtf(var + 1e-5f);
        a2s[c] = a; b2s[c] = beta[c] - mu * a;
    }
    __syncthreads();

    const int mtile = blockIdx.x * 4 + wave;
    if (mtile >= NN / 16) return;
    const int m0 = mtile * 16;
    const int am = m0 + col;

    f32x4 acc;
    acc[0] = acc[1] = acc[2] = acc[3] = 0.f;
    #pragma unroll
    for (int kt = 0; kt < 32; ++kt) {
        const int kk = kt * 32 + q * 8;
        uint4 u = *(const uint4*)(agg + (size_t)am * HID + kk);
        float xv[8];
        unpack8(u, xv);
        unsigned short hv[8];
        #pragma unroll
        for (int j = 0; j < 8; ++j) {
            float v = xv[j] * a2s[kk + j] + b2s[kk + j];
            v = fmaxf(v, 0.01f * v);          // leaky 0.01
            hv[j] = f2bf(fin(v));
        }
        bf16x8 af = __builtin_bit_cast(bf16x8, *(const uint4*)hv);
        bf16x8 bf = __builtin_bit_cast(bf16x8, *(const uint4*)&bs[col * K2P + kk]);
        acc = __builtin_amdgcn_mfma_f32_16x16x32_bf16(af, bf, acc, 0, 0, 0);
    }

    const float bv = (col < 8) ? bl2[col] : br2[col - 8];
    float* outp = (col < 8) ? (xl2 + col) : (xr2 + (col - 8));
    #pragma unroll
    for (int r = 0; r < 4; ++r) {
        const int row = m0 + q * 4 + r;
        outp[row * 8] = fin(acc[r] + bv);
    }
}

// ---------------- GAT2 single-pass (degree-sorted order) ----------------
__global__ __launch_bounds__(256) void gat2_node(
    const float* __restrict__ xl2, const float* __restrict__ xr2,
    const float* __restrict__ att2, const float* __restrict__ bias2,
    const int* __restrict__ offs, const int* __restrict__ ssrc,
    const int* __restrict__ perm,
    float* __restrict__ out) {
    const int lane = threadIdx.x & 63;
    const int wave = threadIdx.x >> 6;
    const int i = perm[blockIdx.x * 4 + wave];
    const int h = lane & 7, slot = lane >> 3;
    const int e0 = offs[i];
    const int e1 = max(offs[i + 1], e0);
    const float xr_h = xr2[i * 8 + h];
    const float att_h = att2[h];
    float ssum = 0.f, wsum = 0.f;
    for (int eb = e0; eb < e1; eb += 8) {
        int e = eb + slot;
        if (e < e1) {
            float xlv = xl2[clampi(ssrc[e]) * 8 + h];
            float v = xlv + xr_h;
            v = fmaxf(v, 0.2f * v);
            float a = __expf(fminf(fin(att_h * v), 50.f));
            ssum += a; wsum += a * xlv;
        }
    }
    ssum += __shfl_xor(ssum, 8); ssum += __shfl_xor(ssum, 16); ssum += __shfl_xor(ssum, 32);
    wsum += __shfl_xor(wsum, 8); wsum += __shfl_xor(wsum, 16); wsum += __shfl_xor(wsum, 32);
    float v = fin(wsum / (ssum + 1e-16f));
    v += __shfl_xor(v, 1); v += __shfl_xor(v, 2); v += __shfl_xor(v, 4);
    if (lane == 0) out[i] = fin(v * 0.125f + bias2[0]);
}

// ---------------- launch ----------------
extern "C" void kernel_launch(void* const* d_in, const int* in_sizes, int n_in,
                              void* d_out, int out_size, void* d_ws, size_t ws_size,
                              hipStream_t stream) {
    float* out = (float*)d_out;   // reference output dtype is float32

    static const int expected[18] = {
        NN * DIN, DIN, DIN, DIN * HID, HID, DIN * HID, HID, HID, HID,
        HID, HID, HID * NH, NH, HID * NH, NH, NH, 1, 2 * E0
    };
    if (n_in != 18) {
        debug_fill<<<(NN + 255) / 256, 256, 0, stream>>>(out, 8192.f + 64.f * (float)n_in);
        return;
    }
    for (int i = 0; i < 18; ++i) {
        if (in_sizes[i] != expected[i]) {
            debug_fill<<<(NN + 255) / 256, 256, 0, stream>>>(out, 4096.f + 32.f * (float)i);
            return;
        }
    }

    const float* x      = (const float*)d_in[0];
    const float* gamma1 = (const float*)d_in[1];
    const float* beta1  = (const float*)d_in[2];
    const float* Wl1    = (const float*)d_in[3];
    const float* bl1    = (const float*)d_in[4];
    const float* Wr1    = (const float*)d_in[5];
    const float* br1    = (const float*)d_in[6];
    const float* att1   = (const float*)d_in[7];
    const float* bias1  = (const float*)d_in[8];
    const float* gamma2 = (const float*)d_in[9];
    const float* beta2  = (const float*)d_in[10];
    const float* Wl2    = (const float*)d_in[11];
    const float* bl2    = (const float*)d_in[12];
    const float* Wr2    = (const float*)d_in[13];
    const float* br2    = (const float*)d_in[14];
    const float* att2   = (const float*)d_in[15];
    const float* bias2  = (const float*)d_in[16];
    const int*   ei     = (const int*)d_in[17];

    char* p = (char*)d_ws;
    auto alloc = [&](size_t bytes) -> void* {
        void* r = (void*)p;
        p += (bytes + 255) & ~(size_t)255;
        return r;
    };
    unsigned short* xl1  = (unsigned short*)alloc((size_t)NN * HID * 2);  // 20.48 MB
    unsigned short* xr1  = (unsigned short*)alloc((size_t)NN * HID * 2);  // 20.48 MB
    unsigned short* agg  = xr1;                                           // ALIAS (see gat1_node)
    unsigned short* hn   = (unsigned short*)alloc((size_t)NN * KP * 2);   // 3.84 MB
    unsigned short* wlt  = (unsigned short*)alloc((size_t)HID * KP * 2);  // 0.39 MB
    unsigned short* wrt  = (unsigned short*)alloc((size_t)HID * KP * 2);  // 0.39 MB
    float*          xl2  = (float*)alloc((size_t)NN * 8 * 4);
    float*          xr2  = (float*)alloc((size_t)NN * 8 * 4);
    int*            offs = (int*)alloc((NN + 1) * 4);
    int*            cur  = (int*)alloc(NN * 4);
    int*            ssrc = (int*)alloc(ET * 4);
    int*            perm = (int*)alloc(NN * 4);
    char* zbase = p;
    float* colsum1 = (float*)alloc(DIN * 4);
    float* colsq1  = (float*)alloc(DIN * 4);
    float* colsum2 = (float*)alloc(HID * 4);
    float* colsq2  = (float*)alloc(HID * 4);
    int*   deg     = (int*)alloc(NN * 4);
    size_t zlen = (size_t)(p - zbase);
    hipMemsetAsync(zbase, 0, zlen, stream);

    // 11 launches (r14: bn2_apply fused into gemm2; degree-sorted perm for gat1/gat2)
    bn1_stats<<<80, 256, 0, stream>>>(x, colsum1, colsq1);
    bn1_apply<<<(NN * KP + 255) / 256, 256, 0, stream>>>(x, colsum1, colsq1, gamma1, beta1, hn);
    w1_transpose<<<dim3(6, 16, 2), 256, 0, stream>>>(Wl1, Wr1, wlt, wrt);
    gemm1_kernel<<<dim3((NN + 127) / 128, HID / 64, 2), 256, 0, stream>>>(hn, wlt, wrt, bl1, br1, xl1, xr1);
    edge_hist<<<(ET + 255) / 256, 256, 0, stream>>>(ei, deg);
    scan_kernel<<<1, 1024, 0, stream>>>(deg, offs, cur, perm);
    edge_scatter<<<(ET + 255) / 256, 256, 0, stream>>>(ei, cur, ssrc);
    gat1_node<<<NN / 4, 256, 0, stream>>>(xl1, xr1, att1, bias1, offs, ssrc, perm, agg);
    bn2_stats<<<80, 256, 0, stream>>>(agg, colsum2, colsq2);
    gemm2_kernel<<<(NN / 16 + 3) / 4, 256, 0, stream>>>(agg, colsum2, colsq2, gamma2, beta2,
                                                        Wl2, Wr2, bl2, br2, xl2, xr2);
    gat2_node<<<NN / 4, 256, 0, stream>>>(xl2, xr2, att2, bias2, offs, ssrc, perm, out);
}

// Round 15
// 278.415 us; speedup vs baseline: 1.0849x; 1.0154x over previous
//
#include <hip/hip_runtime.h>

// ---------------- problem constants ----------------
#define NN   10000     // nodes
#define E0   160000    // raw edges
#define ET   170000    // edges + self loops
#define DIN  165       // input channels
#define KP   192       // DIN padded to 32x for MFMA K-loop
#define HID  1024      // 8 heads * 128
#define NH   8
#define BP   200       // LDS row pitch for gemm1 B-tile (conflict-free, 16B-aligned rows)
#define K2P  1032      // LDS row pitch for gemm2 B

// dtypes (settled r6): ALL float tensors f32, edge_index int32, OUTPUT f32.

typedef __bf16 bf16x8 __attribute__((ext_vector_type(8)));
typedef float  f32x4  __attribute__((ext_vector_type(4)));

__device__ __forceinline__ float bf2f(unsigned short u) {
    unsigned int i = ((unsigned int)u) << 16;
    return __builtin_bit_cast(float, i);
}
__device__ __forceinline__ unsigned short f2bf(float f) {
    unsigned int i = __builtin_bit_cast(unsigned int, f);
    i += 0x7fffu + ((i >> 16) & 1u);   // round-to-nearest-even
    return (unsigned short)(i >> 16);
}
__device__ __forceinline__ float fin(float x) {
    return fminf(fmaxf(x, -1e30f), 1e30f);
}
__device__ __forceinline__ int clampi(int s) {
    return min(max(s, 0), NN - 1);
}
__device__ __forceinline__ void unpack8(uint4 u, float* f) {
    f[0]=bf2f((unsigned short)(u.x)); f[1]=bf2f((unsigned short)(u.x>>16));
    f[2]=bf2f((unsigned short)(u.y)); f[3]=bf2f((unsigned short)(u.y>>16));
    f[4]=bf2f((unsigned short)(u.z)); f[5]=bf2f((unsigned short)(u.z>>16));
    f[6]=bf2f((unsigned short)(u.w)); f[7]=bf2f((unsigned short)(u.w>>16));
}

// ---------------- debug ----------------
__global__ __launch_bounds__(256) void debug_fill(float* __restrict__ out, float val) {
    int i = blockIdx.x * 256 + threadIdx.x;
    if (i < NN) out[i] = val;
}

// ---------------- BN1: column stats over x [NN, DIN] f32 ----------------
__global__ __launch_bounds__(256) void bn1_stats(const float* __restrict__ x,
                                                 float* __restrict__ colsum, float* __restrict__ colsq) {
    int r0 = blockIdx.x * 125;
    int c = threadIdx.x;
    if (c >= DIN) return;
    float acc = 0.f, sq = 0.f;
    for (int r = r0; r < r0 + 125; ++r) {
        float v = x[(size_t)r * DIN + c];
        acc += v; sq += v * v;
    }
    atomicAdd(&colsum[c], acc);
    atomicAdd(&colsq[c], sq);
}

// normalized, K-padded hn [NN,KP] bf16; affine computed inline
__global__ __launch_bounds__(256) void bn1_apply(const float* __restrict__ x,
                                                 const float* __restrict__ colsum, const float* __restrict__ colsq,
                                                 const float* __restrict__ gamma, const float* __restrict__ beta,
                                                 unsigned short* __restrict__ hn) {
    int idx = blockIdx.x * 256 + threadIdx.x;   // NN*KP threads
    if (idx >= NN * KP) return;
    int r = idx / KP, c = idx - r * KP;
    float v = 0.f;
    if (c < DIN) {
        float mu  = colsum[c] * (1.f / NN);
        float var = fmaxf(colsq[c] * (1.f / NN) - mu * mu, 0.f);
        float a = gamma[c] * rsqrtf(var + 1e-5f);
        float b = beta[c] - mu * a;
        v = fin(x[(size_t)r * DIN + c] * a + b);
    }
    hn[idx] = f2bf(v);
}

// ---------------- W1 transpose (LDS-tiled, coalesced both sides) ----------------
__global__ __launch_bounds__(256) void w1_transpose(const float* __restrict__ wl,
                                                    const float* __restrict__ wr,
                                                    unsigned short* __restrict__ wlt,
                                                    unsigned short* __restrict__ wrt) {
    const float* src    = blockIdx.z ? wr  : wl;
    unsigned short* dst = blockIdx.z ? wrt : wlt;
    __shared__ float ts[32][65];
    const int k0 = blockIdx.x * 32;
    const int n0 = blockIdx.y * 64;
    const int tid = threadIdx.x;
    for (int idx = tid; idx < 32 * 64; idx += 256) {
        int k = idx >> 6, n = idx & 63;
        ts[k][n] = (k0 + k < DIN) ? src[(size_t)(k0 + k) * HID + n0 + n] : 0.f;
    }
    __syncthreads();
    for (int idx = tid; idx < 64 * 32; idx += 256) {
        int n = idx >> 5, k = idx & 31;
        dst[(size_t)(n0 + n) * KP + k0 + k] = f2bf(ts[k][n]);
    }
}

// ---------------- GEMM1 (MFMA, r15: L+R merged — one A-load feeds 16 MFMAs) ----------
// Both W-tiles staged (2 x 25.6KB LDS). Was: separate z-slices, each re-reading hn
// (MFMA:A-load 4:1, 2528 blocks, ~40us inferred). Now 8:1, 1264 blocks, hn traffic /2.
__global__ __launch_bounds__(256) void gemm1_kernel(
    const unsigned short* __restrict__ hn,
    const unsigned short* __restrict__ wlt,  // [HID][KP] bf16
    const unsigned short* __restrict__ wrt,
    const float* __restrict__ bl,
    const float* __restrict__ br,
    unsigned short* __restrict__ xl,
    unsigned short* __restrict__ xr) {
    __shared__ unsigned short bs[2][64 * BP];   // 51.2 KB (L, R)
    const int tid  = threadIdx.x;
    const int lane = tid & 63;
    const int wave = tid >> 6;
    const int col  = lane & 15;
    const int q    = lane >> 4;
    const int n0   = blockIdx.y * 64;

    // stage both B-tiles: coalesced uint2 reads, contiguous LDS writes
    for (int idx = tid; idx < 64 * 48 * 2; idx += 256) {
        int z = idx >= 64 * 48;
        int rem = z ? idx - 64 * 48 : idx;
        int r = rem / 48, c = rem - r * 48;
        const unsigned short* wt = z ? wrt : wlt;
        uint2 v = *(const uint2*)(wt + (size_t)(n0 + r) * KP + c * 4);
        *(uint2*)&bs[z][r * BP + c * 4] = v;
    }
    __syncthreads();

    const int mbase = blockIdx.x * 128 + wave * 32;
    const int am0 = mbase + col;
    const int am1 = am0 + 16;
    const bool aok0 = (am0 < NN), aok1 = (am1 < NN);

    f32x4 accL[2][4], accR[2][4];
    #pragma unroll
    for (int m = 0; m < 2; ++m)
        for (int nt = 0; nt < 4; ++nt)
            for (int r = 0; r < 4; ++r) { accL[m][nt][r] = 0.f; accR[m][nt][r] = 0.f; }

    #pragma unroll
    for (int kt = 0; kt < 6; ++kt) {
        const int kk = kt * 32 + q * 8;
        uint4 a0u = make_uint4(0u,0u,0u,0u), a1u = make_uint4(0u,0u,0u,0u);
        if (aok0) a0u = *(const uint4*)(hn + (size_t)am0 * KP + kk);
        if (aok1) a1u = *(const uint4*)(hn + (size_t)am1 * KP + kk);
        bf16x8 a0 = __builtin_bit_cast(bf16x8, a0u);
        bf16x8 a1 = __builtin_bit_cast(bf16x8, a1u);
        #pragma unroll
        for (int nt = 0; nt < 4; ++nt) {
            bf16x8 bfl = __builtin_bit_cast(bf16x8, *(const uint4*)&bs[0][(nt * 16 + col) * BP + kk]);
            accL[0][nt] = __builtin_amdgcn_mfma_f32_16x16x32_bf16(a0, bfl, accL[0][nt], 0, 0, 0);
            accL[1][nt] = __builtin_amdgcn_mfma_f32_16x16x32_bf16(a1, bfl, accL[1][nt], 0, 0, 0);
            bf16x8 bfr = __builtin_bit_cast(bf16x8, *(const uint4*)&bs[1][(nt * 16 + col) * BP + kk]);
            accR[0][nt] = __builtin_amdgcn_mfma_f32_16x16x32_bf16(a0, bfr, accR[0][nt], 0, 0, 0);
            accR[1][nt] = __builtin_amdgcn_mfma_f32_16x16x32_bf16(a1, bfr, accR[1][nt], 0, 0, 0);
        }
    }

    #pragma unroll
    for (int nt = 0; nt < 4; ++nt) {
        const int nc = n0 + nt * 16 + col;
        const float bLv = bl[nc];
        const float bRv = br[nc];
        #pragma unroll
        for (int m = 0; m < 2; ++m) {
            #pragma unroll
            for (int r = 0; r < 4; ++r) {
                const int row = mbase + m * 16 + q * 4 + r;
                if (row < NN) {
                    xl[(size_t)row * HID + nc] = f2bf(fin(accL[m][nt][r] + bLv));
                    xr[(size_t)row * HID + nc] = f2bf(fin(accR[m][nt][r] + bRv));
                }
            }
        }
    }
}

// ---------------- edge counting-sort by dst ----------------
__global__ __launch_bounds__(256) void edge_hist(const int* __restrict__ ei, int* __restrict__ deg) {
    int e = blockIdx.x * 256 + threadIdx.x;
    if (e >= ET) return;
    int d = (e < E0) ? ei[E0 + e] : (e - E0);
    atomicAdd(&deg[clampi(d)], 1);
}

// single-block scan + degree-descending node permutation
__global__ __launch_bounds__(1024) void scan_kernel(const int* __restrict__ deg,
                                                    int* __restrict__ offs, int* __restrict__ cur,
                                                    int* __restrict__ perm) {
    __shared__ int wsum[16];
    __shared__ int bins[64];
    __shared__ int bcur[64];
    const int tid = threadIdx.x;
    const int base = tid * 10;
    int loc[10];
    int run = 0;
    #pragma unroll
    for (int j = 0; j < 10; ++j) {
        int idx = base + j;
        int v = (idx < NN) ? deg[idx] : 0;
        loc[j] = run;
        run += v;
    }
    const int lane = tid & 63;
    const int w = tid >> 6;
    int inc = run;
    #pragma unroll
    for (int s = 1; s < 64; s <<= 1) {
        int t = __shfl_up(inc, s);
        if (lane >= s) inc += t;
    }
    if (lane == 63) wsum[w] = inc;
    if (tid < 64) bins[tid] = 0;
    __syncthreads();
    int woff = 0;
    #pragma unroll
    for (int k = 0; k < 16; ++k) woff += (k < w) ? wsum[k] : 0;
    const int toff = woff + inc - run;
    #pragma unroll
    for (int j = 0; j < 10; ++j) {
        int idx = base + j;
        if (idx < NN) {
            int e = toff + loc[j]; offs[idx] = e; cur[idx] = e;
            atomicAdd(&bins[63 - min(deg[idx], 63)], 1);   // descending-degree bucket
        }
    }
    if (tid == 1023) offs[NN] = woff + inc;
    __syncthreads();
    if (tid < 64) {   // wave 0: exclusive scan of 64 bins
        int v = bins[tid];
        int binc = v;
        #pragma unroll
        for (int s = 1; s < 64; s <<= 1) {
            int t = __shfl_up(binc, s);
            if (tid >= s) binc += t;
        }
        bcur[tid] = binc - v;
    }
    __syncthreads();
    #pragma unroll
    for (int j = 0; j < 10; ++j) {
        int idx = base + j;
        if (idx < NN) {
            int pos = atomicAdd(&bcur[63 - min(deg[idx], 63)], 1);
            perm[pos] = idx;
        }
    }
}

__global__ __launch_bounds__(256) void edge_scatter(const int* __restrict__ ei,
                                                    int* __restrict__ cur, int* __restrict__ ssrc) {
    int e = blockIdx.x * 256 + threadIdx.x;
    if (e >= ET) return;
    int s, d;
    if (e < E0) { s = ei[e]; d = ei[E0 + e]; }
    else        { s = e - E0; d = e - E0; }
    int pos = atomicAdd(&cur[clampi(d)], 1);
    if (pos >= 0 && pos < ET) ssrc[pos] = clampi(s);
}

// ---------------- GAT1 wave-per-node (degree-sorted order): -> agg bf16 ----
// Registers only; alias (agg=xr1) safe by program order within the wave (same row i).
__global__ __launch_bounds__(256) void gat1_node(
    const unsigned short* __restrict__ xl1, const unsigned short* xr1,
    const float* __restrict__ att1, const float* __restrict__ bias1,
    const int* __restrict__ offs, const int* __restrict__ ssrc,
    const int* __restrict__ perm,
    unsigned short* agg) {
    const int lane = threadIdx.x & 63;
    const int wave = threadIdx.x >> 6;
    const int i = perm[blockIdx.x * 4 + wave];   // degree-descending: long nodes start first
    const int e0 = offs[i];
    const int e1 = max(offs[i + 1], e0);

    float xr_r[16], att_r[16];
    {
        const uint4* xp = (const uint4*)(xr1 + (size_t)i * HID + lane * 16);
        uint4 u0 = xp[0], u1 = xp[1];
        unpack8(u0, xr_r); unpack8(u1, xr_r + 8);
        const float4* ap = (const float4*)(att1 + lane * 16);
        float4 a0 = ap[0], a1 = ap[1], a2 = ap[2], a3 = ap[3];
        att_r[0]=a0.x; att_r[1]=a0.y; att_r[2]=a0.z; att_r[3]=a0.w;
        att_r[4]=a1.x; att_r[5]=a1.y; att_r[6]=a1.z; att_r[7]=a1.w;
        att_r[8]=a2.x; att_r[9]=a2.y; att_r[10]=a2.z; att_r[11]=a2.w;
        att_r[12]=a3.x; att_r[13]=a3.y; att_r[14]=a3.z; att_r[15]=a3.w;
    }

    float o[16];
    #pragma unroll
    for (int j = 0; j < 16; ++j) o[j] = 0.f;
    float s = 0.f;

    int e = e0;
    for (; e + 1 < e1; e += 2) {
        const int s0i = clampi(ssrc[e]);
        const int s1i = clampi(ssrc[e + 1]);
        const uint4* xp0 = (const uint4*)(xl1 + (size_t)s0i * HID + lane * 16);
        const uint4* xp1 = (const uint4*)(xl1 + (size_t)s1i * HID + lane * 16);
        uint4 a0 = xp0[0], a1 = xp0[1], b0 = xp1[0], b1 = xp1[1];
        float xv0[16], xv1[16];
        unpack8(a0, xv0); unpack8(a1, xv0 + 8);
        unpack8(b0, xv1); unpack8(b1, xv1 + 8);
        float p0 = 0.f, p1 = 0.f;
        #pragma unroll
        for (int j = 0; j < 16; ++j) {
            float v0 = xv0[j] + xr_r[j];
            float v1 = xv1[j] + xr_r[j];
            v0 = fmaxf(v0, 0.2f * v0);
            v1 = fmaxf(v1, 0.2f * v1);
            p0 = fmaf(att_r[j], v0, p0);
            p1 = fmaf(att_r[j], v1, p1);
        }
        p0 += __shfl_xor(p0, 1); p0 += __shfl_xor(p0, 2); p0 += __shfl_xor(p0, 4);
        p1 += __shfl_xor(p1, 1); p1 += __shfl_xor(p1, 2); p1 += __shfl_xor(p1, 4);
        const float aa0 = __expf(fminf(fin(p0), 50.f));
        const float aa1 = __expf(fminf(fin(p1), 50.f));
        s += aa0 + aa1;
        #pragma unroll
        for (int j = 0; j < 16; ++j) o[j] = fmaf(aa0, xv0[j], fmaf(aa1, xv1[j], o[j]));
    }
    if (e < e1) {
        const int sidx = clampi(ssrc[e]);
        const uint4* xp = (const uint4*)(xl1 + (size_t)sidx * HID + lane * 16);
        uint4 u0 = xp[0], u1 = xp[1];
        float xv[16];
        unpack8(u0, xv); unpack8(u1, xv + 8);
        float p = 0.f;
        #pragma unroll
        for (int j = 0; j < 16; ++j) {
            float v = xv[j] + xr_r[j];
            v = fmaxf(v, 0.2f * v);
            p = fmaf(att_r[j], v, p);
        }
        p += __shfl_xor(p, 1); p += __shfl_xor(p, 2); p += __shfl_xor(p, 4);
        const float a = __expf(fminf(fin(p), 50.f));
        s += a;
        #pragma unroll
        for (int j = 0; j < 16; ++j) o[j] = fmaf(a, xv[j], o[j]);
    }

    const float inv = 1.f / (s + 1e-16f);
    const float4* bp = (const float4*)(bias1 + lane * 16);
    float4 b0 = bp[0], b1 = bp[1], b2 = bp[2], b3 = bp[3];
    float bb[16] = {b0.x,b0.y,b0.z,b0.w, b1.x,b1.y,b1.z,b1.w,
                    b2.x,b2.y,b2.z,b2.w, b3.x,b3.y,b3.z,b3.w};
    unsigned short ov[16];
    #pragma unroll
    for (int j = 0; j < 16; ++j) ov[j] = f2bf(fin(o[j] * inv + bb[j]));
    uint4* op = (uint4*)(agg + (size_t)i * HID + lane * 16);
    op[0] = *(const uint4*)&ov[0];
    op[1] = *(const uint4*)&ov[8];
}

// ---------------- BN2 stats over agg [NN,HID] bf16 ----------------
__global__ __launch_bounds__(256) void bn2_stats(const unsigned short* __restrict__ agg,
                                                 float* __restrict__ colsum, float* __restrict__ colsq) {
    int r0 = blockIdx.x * 125;
    int t = threadIdx.x;
    float s0=0,s1=0,s2=0,s3=0,q0=0,q1=0,q2=0,q3=0;
    for (int r = r0; r < r0 + 125; ++r) {
        const ushort4 u = *(const ushort4*)(agg + (size_t)r * HID + t * 4);
        float v0=bf2f(u.x), v1=bf2f(u.y), v2=bf2f(u.z), v3=bf2f(u.w);
        s0+=v0; q0+=v0*v0; s1+=v1; q1+=v1*v1;
        s2+=v2; q2+=v2*v2; s3+=v3; q3+=v3*v3;
    }
    atomicAdd(&colsum[t*4+0], s0); atomicAdd(&colsq[t*4+0], q0);
    atomicAdd(&colsum[t*4+1], s1); atomicAdd(&colsq[t*4+1], q1);
    atomicAdd(&colsum[t*4+2], s2); atomicAdd(&colsq[t*4+2], q2);
    atomicAdd(&colsum[t*4+3], s3); atomicAdd(&colsq[t*4+3], q3);
}

// ---------------- GEMM2 (MFMA, BN2 affine + leaky fused into A-path) -----------
__global__ __launch_bounds__(256) void gemm2_kernel(
    const unsigned short* __restrict__ agg,
    const float* __restrict__ colsum, const float* __restrict__ colsq,
    const float* __restrict__ gamma, const float* __restrict__ beta,
    const float* __restrict__ wl2, const float* __restrict__ wr2,
    const float* __restrict__ bl2, const float* __restrict__ br2,
    float* __restrict__ xl2, float* __restrict__ xr2) {
    __shared__ unsigned short bs[16 * K2P];   // 33 KB
    __shared__ float a2s[HID], b2s[HID];      // 8 KB affine table
    const int tid  = threadIdx.x;
    const int lane = tid & 63;
    const int wave = tid >> 6;
    const int col  = lane & 15;
    const int q    = lane >> 4;

    for (int idx = tid; idx < 16 * HID; idx += 256) {
        int n = idx >> 10, k = idx & (HID - 1);
        float v = (n < 8) ? wl2[k * 8 + n] : wr2[k * 8 + (n - 8)];
        bs[n * K2P + k] = f2bf(v);
    }
    for (int c = tid; c < HID; c += 256) {
        float mu  = colsum[c] * (1.f / NN);
        float var = fmaxf(colsq[c] * (1.f / NN) - mu * mu, 0.f);
        float a = gamma[c] * rsqrtf(var + 1e-5f);
        a2s[c] = a; b2s[c] = beta[c] - mu * a;
    }
    __syncthreads();

    const int mtile = blockIdx.x * 4 + wave;
    if (mtile >= NN / 16) return;
    const int m0 = mtile * 16;
    const int am = m0 + col;

    f32x4 acc;
    acc[0] = acc[1] = acc[2] = acc[3] = 0.f;
    #pragma unroll
    for (int kt = 0; kt < 32; ++kt) {
        const int kk = kt * 32 + q * 8;
        uint4 u = *(const uint4*)(agg + (size_t)am * HID + kk);
        float xv[8];
        unpack8(u, xv);
        unsigned short hv[8];
        #pragma unroll
        for (int j = 0; j < 8; ++j) {
            float v = xv[j] * a2s[kk + j] + b2s[kk + j];
            v = fmaxf(v, 0.01f * v);          // leaky 0.01
            hv[j] = f2bf(fin(v));
        }
        bf16x8 af = __builtin_bit_cast(bf16x8, *(const uint4*)hv);
        bf16x8 bf = __builtin_bit_cast(bf16x8, *(const uint4*)&bs[col * K2P + kk]);
        acc = __builtin_amdgcn_mfma_f32_16x16x32_bf16(af, bf, acc, 0, 0, 0);
    }

    const float bv = (col < 8) ? bl2[col] : br2[col - 8];
    float* outp = (col < 8) ? (xl2 + col) : (xr2 + (col - 8));
    #pragma unroll
    for (int r = 0; r < 4; ++r) {
        const int row = m0 + q * 4 + r;
        outp[row * 8] = fin(acc[r] + bv);
    }
}

// ---------------- GAT2 single-pass (degree-sorted order) ----------------
__global__ __launch_bounds__(256) void gat2_node(
    const float* __restrict__ xl2, const float* __restrict__ xr2,
    const float* __restrict__ att2, const float* __restrict__ bias2,
    const int* __restrict__ offs, const int* __restrict__ ssrc,
    const int* __restrict__ perm,
    float* __restrict__ out) {
    const int lane = threadIdx.x & 63;
    const int wave = threadIdx.x >> 6;
    const int i = perm[blockIdx.x * 4 + wave];
    const int h = lane & 7, slot = lane >> 3;
    const int e0 = offs[i];
    const int e1 = max(offs[i + 1], e0);
    const float xr_h = xr2[i * 8 + h];
    const float att_h = att2[h];
    float ssum = 0.f, wsum = 0.f;
    for (int eb = e0; eb < e1; eb += 8) {
        int e = eb + slot;
        if (e < e1) {
            float xlv = xl2[clampi(ssrc[e]) * 8 + h];
            float v = xlv + xr_h;
            v = fmaxf(v, 0.2f * v);
            float a = __expf(fminf(fin(att_h * v), 50.f));
            ssum += a; wsum += a * xlv;
        }
    }
    ssum += __shfl_xor(ssum, 8); ssum += __shfl_xor(ssum, 16); ssum += __shfl_xor(ssum, 32);
    wsum += __shfl_xor(wsum, 8); wsum += __shfl_xor(wsum, 16); wsum += __shfl_xor(wsum, 32);
    float v = fin(wsum / (ssum + 1e-16f));
    v += __shfl_xor(v, 1); v += __shfl_xor(v, 2); v += __shfl_xor(v, 4);
    if (lane == 0) out[i] = fin(v * 0.125f + bias2[0]);
}

// ---------------- launch ----------------
extern "C" void kernel_launch(void* const* d_in, const int* in_sizes, int n_in,
                              void* d_out, int out_size, void* d_ws, size_t ws_size,
                              hipStream_t stream) {
    float* out = (float*)d_out;   // reference output dtype is float32

    static const int expected[18] = {
        NN * DIN, DIN, DIN, DIN * HID, HID, DIN * HID, HID, HID, HID,
        HID, HID, HID * NH, NH, HID * NH, NH, NH, 1, 2 * E0
    };
    if (n_in != 18) {
        debug_fill<<<(NN + 255) / 256, 256, 0, stream>>>(out, 8192.f + 64.f * (float)n_in);
        return;
    }
    for (int i = 0; i < 18; ++i) {
        if (in_sizes[i] != expected[i]) {
            debug_fill<<<(NN + 255) / 256, 256, 0, stream>>>(out, 4096.f + 32.f * (float)i);
            return;
        }
    }

    const float* x      = (const float*)d_in[0];
    const float* gamma1 = (const float*)d_in[1];
    const float* beta1  = (const float*)d_in[2];
    const float* Wl1    = (const float*)d_in[3];
    const float* bl1    = (const float*)d_in[4];
    const float* Wr1    = (const float*)d_in[5];
    const float* br1    = (const float*)d_in[6];
    const float* att1   = (const float*)d_in[7];
    const float* bias1  = (const float*)d_in[8];
    const float* gamma2 = (const float*)d_in[9];
    const float* beta2  = (const float*)d_in[10];
    const float* Wl2    = (const float*)d_in[11];
    const float* bl2    = (const float*)d_in[12];
    const float* Wr2    = (const float*)d_in[13];
    const float* br2    = (const float*)d_in[14];
    const float* att2   = (const float*)d_in[15];
    const float* bias2  = (const float*)d_in[16];
    const int*   ei     = (const int*)d_in[17];

    char* p = (char*)d_ws;
    auto alloc = [&](size_t bytes) -> void* {
        void* r = (void*)p;
        p += (bytes + 255) & ~(size_t)255;
        return r;
    };
    unsigned short* xl1  = (unsigned short*)alloc((size_t)NN * HID * 2);  // 20.48 MB
    unsigned short* xr1  = (unsigned short*)alloc((size_t)NN * HID * 2);  // 20.48 MB
    unsigned short* agg  = xr1;                                           // ALIAS (see gat1_node)
    unsigned short* hn   = (unsigned short*)alloc((size_t)NN * KP * 2);   // 3.84 MB
    unsigned short* wlt  = (unsigned short*)alloc((size_t)HID * KP * 2);  // 0.39 MB
    unsigned short* wrt  = (unsigned short*)alloc((size_t)HID * KP * 2);  // 0.39 MB
    float*          xl2  = (float*)alloc((size_t)NN * 8 * 4);
    float*          xr2  = (float*)alloc((size_t)NN * 8 * 4);
    int*            offs = (int*)alloc((NN + 1) * 4);
    int*            cur  = (int*)alloc(NN * 4);
    int*            ssrc = (int*)alloc(ET * 4);
    int*            perm = (int*)alloc(NN * 4);
    char* zbase = p;
    float* colsum1 = (float*)alloc(DIN * 4);
    float* colsq1  = (float*)alloc(DIN * 4);
    float* colsum2 = (float*)alloc(HID * 4);
    float* colsq2  = (float*)alloc(HID * 4);
    int*   deg     = (int*)alloc(NN * 4);
    size_t zlen = (size_t)(p - zbase);
    hipMemsetAsync(zbase, 0, zlen, stream);

    // 11 launches (r15: gemm1 L+R merged into one dispatch)
    bn1_stats<<<80, 256, 0, stream>>>(x, colsum1, colsq1);
    bn1_apply<<<(NN * KP + 255) / 256, 256, 0, stream>>>(x, colsum1, colsq1, gamma1, beta1, hn);
    w1_transpose<<<dim3(6, 16, 2), 256, 0, stream>>>(Wl1, Wr1, wlt, wrt);
    gemm1_kernel<<<dim3((NN + 127) / 128, HID / 64), 256, 0, stream>>>(hn, wlt, wrt, bl1, br1, xl1, xr1);
    edge_hist<<<(ET + 255) / 256, 256, 0, stream>>>(ei, deg);
    scan_kernel<<<1, 1024, 0, stream>>>(deg, offs, cur, perm);
    edge_scatter<<<(ET + 255) / 256, 256, 0, stream>>>(ei, cur, ssrc);
    gat1_node<<<NN / 4, 256, 0, stream>>>(xl1, xr1, att1, bias1, offs, ssrc, perm, agg);
    bn2_stats<<<80, 256, 0, stream>>>(agg, colsum2, colsq2);
    gemm2_kernel<<<(NN / 16 + 3) / 4, 256, 0, stream>>>(agg, colsum2, colsq2, gamma2, beta2,
                                                        Wl2, Wr2, bl2, br2, xl2, xr2);
    gat2_node<<<NN / 4, 256, 0, stream>>>(xl2, xr2, att2, bias2, offs, ssrc, perm, out);
}